// Round 8
// baseline (490.102 us; speedup 1.0000x reference)
//
#include <hip/hip_runtime.h>
#include <hip/hip_bf16.h>
#include <math.h>

#define B_ 2
#define T_ 2048
#define H_ 16
#define S_ 64
#define EMB 1024
#define FF 4096
#define BT (B_*T_)        // 4096 rows
#define ROWS (B_*T_*H_)   // 65536

typedef __attribute__((ext_vector_type(8))) short s16x8;   // 8 bf16 (4 VGPRs)
typedef __attribute__((ext_vector_type(4))) float f32x4;   // MFMA C/D

struct P4 { unsigned short* p[4]; };   // partial-sum pointers (bf16)

__device__ __forceinline__ unsigned short f2b(float f) {
    return __builtin_bit_cast(unsigned short, __float2bfloat16(f));
}
__device__ __forceinline__ float b2f(short u) {
    return __builtin_bit_cast(float, ((unsigned int)(unsigned short)u) << 16);
}

// async global->LDS, 16B per lane (LDS dest = wave-uniform base + lane*16;
// GLOBAL address may be fully per-lane - only the LDS side is constrained)
__device__ __forceinline__ void gl_lds16(const void* g, void* l) {
    __builtin_amdgcn_global_load_lds(
        (const __attribute__((address_space(1))) void*)g,
        (__attribute__((address_space(3))) void*)l, 16, 0, 0);
}

__device__ __forceinline__ f32x4 mfma16(s16x8 a, s16x8 b, f32x4 c) {
    return __builtin_amdgcn_mfma_f32_16x16x32_bf16(a, b, c, 0, 0, 0);
}

// s_waitcnt simm16 (gfx9): vmcnt[3:0]|hi[15:14], expcnt[6:4], lgkmcnt[11:8]
#define WAIT_VM2 0x0F72   // vmcnt(2)
#define WAIT_VM0 0x0F70   // vmcnt(0)

// ---------------------------------------------------------------------------
// Kernel 1: kqv, MFMA version. x [ROWS][64] fp32, Wqt [192][64] bf16.
// Outputs K,Q,V bf16 in x-row order: [ (b*T+t)*H+h ][64].
// ---------------------------------------------------------------------------
__global__ __launch_bounds__(256) void kqv_kernel(const float* __restrict__ x,
        const unsigned short* __restrict__ Wqt, unsigned short* __restrict__ K,
        unsigned short* __restrict__ Q, unsigned short* __restrict__ V) {
    const int tid = threadIdx.x;
    const int w = tid >> 6, lane = tid & 63;
    const int l15 = lane & 15, quad = lane >> 4;
    const long r0 = (long)blockIdx.x * 128 + w * 32;

    s16x8 af[2][2];
    #pragma unroll
    for (int mt = 0; mt < 2; ++mt)
        #pragma unroll
        for (int ks = 0; ks < 2; ++ks) {
            const float* xp = x + (r0 + mt*16 + l15) * 64 + ks*32 + quad*8;
            const float4 v0 = *(const float4*)xp;
            const float4 v1 = *(const float4*)(xp + 4);
            s16x8 a;
            a[0] = (short)f2b(v0.x); a[1] = (short)f2b(v0.y);
            a[2] = (short)f2b(v0.z); a[3] = (short)f2b(v0.w);
            a[4] = (short)f2b(v1.x); a[5] = (short)f2b(v1.y);
            a[6] = (short)f2b(v1.z); a[7] = (short)f2b(v1.w);
            af[mt][ks] = a;
        }

    #pragma unroll
    for (int nt = 0; nt < 12; ++nt) {
        const s16x8 b0 = *(const s16x8*)&Wqt[(nt*16 + l15)*64 + quad*8];
        const s16x8 b1 = *(const s16x8*)&Wqt[(nt*16 + l15)*64 + 32 + quad*8];
        f32x4 acc[2] = {};
        #pragma unroll
        for (int mt = 0; mt < 2; ++mt) {
            acc[mt] = mfma16(af[mt][0], b0, acc[mt]);
            acc[mt] = mfma16(af[mt][1], b1, acc[mt]);
        }
        unsigned short* dst = (nt < 4) ? K : (nt < 8) ? Q : V;
        const int c0 = (nt & 3) * 16 + l15;
        #pragma unroll
        for (int mt = 0; mt < 2; ++mt)
            #pragma unroll
            for (int r = 0; r < 4; ++r)
                dst[(r0 + mt*16 + quad*4 + r) * 64 + c0] = f2b(acc[mt][r]);
    }
}

// ---------------------------------------------------------------------------
// Kernel 1b: V [ (b,t,h) ][d] -> VT [bh][d][t]  (64x64 tiles per (b,h))
// ---------------------------------------------------------------------------
__global__ __launch_bounds__(256) void vt_kernel(const unsigned short* __restrict__ V,
        unsigned short* __restrict__ VT) {
    __shared__ unsigned short Ts[64][72];
    const int tid = threadIdx.x;
    const int tt = blockIdx.x, bh = blockIdx.y;
    const int b = bh >> 4, h = bh & 15;
    const long vbase = ((long)b * (T_*H_) + h) * 64;   // + t*1024 + d
    #pragma unroll
    for (int i = 0; i < 2; ++i) {
        const int id = i * 256 + tid;          // 0..511
        const int tr = id >> 3, dc = (id & 7) * 8;
        const s16x8 v = *(const s16x8*)&V[vbase + (long)(tt*64 + tr)*1024 + dc];
        *(s16x8*)&Ts[tr][dc] = v;
    }
    __syncthreads();
    #pragma unroll
    for (int i = 0; i < 2; ++i) {
        const int id = i * 256 + tid;
        const int d = id >> 3, tc = (id & 7) * 8;
        s16x8 o;
        #pragma unroll
        for (int j = 0; j < 8; ++j) o[j] = (short)Ts[tc + j][d];
        *(s16x8*)&VT[((long)bh*64 + d)*2048 + tt*64 + tc] = o;
    }
}

// ---------------------------------------------------------------------------
// Kernel 2 (R6): flash attention, 4-wave blocks, kv-split=2, swizzled LDS.
// K/V LDS reads conflict-free via source-side swizzle + XOR'd read chunk.
// Ps pad 40 for 16B-aligned conflict-free P reloads.
// ---------------------------------------------------------------------------
__global__ __launch_bounds__(256) void attn_kernel(const unsigned short* __restrict__ Q,
        const unsigned short* __restrict__ K, const unsigned short* __restrict__ VT,
        unsigned short* __restrict__ Op, float* __restrict__ lp) {
    __shared__ __align__(16) unsigned short Kbuf[2][2][32*32];  // [buf][dhalf][j][d32]
    __shared__ __align__(16) unsigned short Vbuf[2][64*32];     // [buf][d][t32]
    __shared__ __align__(16) unsigned short Ps[4][32*40];       // per-wave [q][j], pad 40
    const int tid = threadIdx.x;
    const int wid = tid >> 6, lane = tid & 63;
    const int l15 = lane & 15, quad = lane >> 4;
    const int bid = blockIdx.x;
    const int s = blockIdx.y;                 // kv-split index (0,1)
    const int qg = bid & 15, bh = bid >> 4;   // 16 q-groups consecutive -> L2 locality per bh
    const long base = ((long)(bh >> 4) * (T_*H_) + (bh & 15)) * 64;  // x-row order
    const unsigned short* Qp = Q + base;
    const unsigned short* Kp = K + base;
    const unsigned short* Vp = VT + (long)bh * 64 * 2048;   // [d][t]
    const int q0 = qg * 128 + wid * 32;
    const int kt0 = s * 32;                   // 32 key-tiles per split
    unsigned short* ps = &Ps[wid][0];
    const int rk = (l15 >> 1) & 3;            // read-side swizzle key
    const int sc8 = ((lane & 3) ^ ((lane >> 3) & 3)) * 8;   // staged source chunk

    // Q fragments (B-operand layout), pre-scaled by 1/8 (exact in bf16)
    s16x8 qf[2][2];
    #pragma unroll
    for (int qq = 0; qq < 2; ++qq)
        #pragma unroll
        for (int ks = 0; ks < 2; ++ks) {
            const s16x8 raw = *(const s16x8*)&Qp[(long)(q0 + qq*16 + l15)*1024 + ks*32 + quad*8];
            s16x8 q;
            #pragma unroll
            for (int j = 0; j < 8; ++j) q[j] = (short)f2b(b2f(raw[j]) * 0.125f);
            qf[qq][ks] = q;
        }

    s16x8 onef;
    #pragma unroll
    for (int j = 0; j < 8; ++j) onef[j] = (short)0x3F80;   // bf16 1.0

    f32x4 oacc[2][4] = {};
    f32x4 lacc[2] = {};

    const int j16 = lane >> 2;           // staging row within 16-row call

    // stage: 8 x 1KB gl_lds calls split across 4 waves (2 per wave).
    // Global source column carries the inverse swizzle (sc8).
    auto stage = [&](int bufi, int kt) {
        char* kl = (char*)&Kbuf[bufi][0][0];
        char* vl = (char*)&Vbuf[bufi][0];
        const unsigned short* kg = Kp + (long)(kt*32) * 1024;
        const unsigned short* vg = Vp + kt*32 + sc8;
        switch (wid) {
        case 0:
            gl_lds16(kg + (long)j16*1024 + sc8,           kl +    0 + lane*16);
            gl_lds16(kg + (long)(j16+16)*1024 + sc8,      kl + 1024 + lane*16);
            break;
        case 1:
            gl_lds16(kg + (long)j16*1024 + 32 + sc8,      kl + 2048 + lane*16);
            gl_lds16(kg + (long)(j16+16)*1024 + 32 + sc8, kl + 3072 + lane*16);
            break;
        case 2:
            gl_lds16(vg + (long)(j16     )*2048, vl +    0 + lane*16);
            gl_lds16(vg + (long)(j16 + 16)*2048, vl + 1024 + lane*16);
            break;
        default:
            gl_lds16(vg + (long)(j16 + 32)*2048, vl + 2048 + lane*16);
            gl_lds16(vg + (long)(j16 + 48)*2048, vl + 3072 + lane*16);
            break;
        }
    };

    auto compute = [&](int bufi) {
        // S^T = K Q^T : A=K from LDS (swizzled read), B=Q regs
        f32x4 sT[2][2] = {};
        #pragma unroll
        for (int ks = 0; ks < 2; ++ks)
            #pragma unroll
            for (int jt = 0; jt < 2; ++jt) {
                const s16x8 kf = *(const s16x8*)&Kbuf[bufi][ks][(jt*16 + l15)*32 + (quad ^ rk)*8];
                sT[jt][0] = mfma16(kf, qf[0][ks], sT[jt][0]);
                sT[jt][1] = mfma16(kf, qf[1][ks], sT[jt][1]);
            }
        // P = exp(S): pack 4 j-consecutive values -> b64 store to ps[q][j]
        #pragma unroll
        for (int jt = 0; jt < 2; ++jt)
            #pragma unroll
            for (int qq = 0; qq < 2; ++qq) {
                uint2 pk;
                pk.x = (unsigned int)f2b(__expf(sT[jt][qq][0]))
                     | ((unsigned int)f2b(__expf(sT[jt][qq][1])) << 16);
                pk.y = (unsigned int)f2b(__expf(sT[jt][qq][2]))
                     | ((unsigned int)f2b(__expf(sT[jt][qq][3])) << 16);
                *(uint2*)&ps[(qq*16 + l15)*40 + jt*16 + quad*4] = pk;
            }
        // O += P V ; l += P 1   (wave-private LDS, DS in-order per wave)
        s16x8 pf[2];
        #pragma unroll
        for (int qq = 0; qq < 2; ++qq) {
            pf[qq] = *(const s16x8*)&ps[(qq*16 + l15)*40 + quad*8];
            lacc[qq] = mfma16(pf[qq], onef, lacc[qq]);
        }
        #pragma unroll
        for (int nt = 0; nt < 4; ++nt) {
            const s16x8 vf = *(const s16x8*)&Vbuf[bufi][(nt*16 + l15)*32 + (quad ^ rk)*8];
            oacc[0][nt] = mfma16(pf[0], vf, oacc[0][nt]);
            oacc[1][nt] = mfma16(pf[1], vf, oacc[1][nt]);
        }
    };

    stage(0, kt0);
    for (int kt = 0; kt < 31; ++kt) {
        stage((kt + 1) & 1, kt0 + kt + 1);           // prefetch next tile
        __builtin_amdgcn_s_waitcnt(WAIT_VM2);        // own 2 loads of tile kt landed
        __builtin_amdgcn_s_barrier();                // all waves' tile-kt loads landed
        __builtin_amdgcn_sched_barrier(0);
        compute(kt & 1);
        __builtin_amdgcn_s_barrier();                // buf kt&1 readers done before t+2 overwrite
        __builtin_amdgcn_sched_barrier(0);
    }
    __builtin_amdgcn_s_waitcnt(WAIT_VM0);
    __builtin_amdgcn_s_barrier();
    __builtin_amdgcn_sched_barrier(0);
    compute(1);   // kt = 31 (31 & 1 = 1)

    // epilogue: unnormalized O partial (bf16) + l partial (fp32).
    // Op layout [s][bh][t][d], lp layout [s][bh][t]; combined later.
    unsigned short* op = Op + ((long)s * 32 + bh) * 2048 * 64;
    float* lrow = lp + ((long)s * 32 + bh) * 2048;
    #pragma unroll
    for (int qq = 0; qq < 2; ++qq)
        #pragma unroll
        for (int r = 0; r < 4; ++r) {
            const int t = q0 + qq*16 + quad*4 + r;
            if (l15 == 0) lrow[t] = lacc[qq][r];
            #pragma unroll
            for (int nt = 0; nt < 4; ++nt)
                op[(long)t*64 + nt*16 + l15] = f2b(oacc[qq][nt][r]);
        }
}

// ---------------------------------------------------------------------------
// Kernel 2b (R3): combine kv-split partials: res = (O0+O1)/(l0+l1),
// written in x-row order [(b*T+t)*EMB + h*64 + d] for the Wproj GEMM.
// ---------------------------------------------------------------------------
__global__ __launch_bounds__(256) void attn_combine(const unsigned short* __restrict__ Op,
        const float* __restrict__ lp, unsigned short* __restrict__ res) {
    const int gid = blockIdx.x * 256 + threadIdx.x;
    const int row = gid >> 4;              // bh*2048 + t
    const int c4 = (gid & 15) * 4;
    const int bh = row >> 11, t = row & 2047;
    const int b = bh >> 4, h = bh & 15;
    const float inv = 1.f / (lp[row] + lp[ROWS + row]);
    const ushort4 u0 = *(const ushort4*)&Op[(long)row * 64 + c4];
    const ushort4 u1 = *(const ushort4*)&Op[((long)ROWS + row) * 64 + c4];
    unsigned short* r = res + ((long)(b*T_ + t)) * EMB + h*64 + c4;
    r[0] = f2b((b2f((short)u0.x) + b2f((short)u1.x)) * inv);
    r[1] = f2b((b2f((short)u0.y) + b2f((short)u1.y)) * inv);
    r[2] = f2b((b2f((short)u0.z) + b2f((short)u1.z)) * inv);
    r[3] = f2b((b2f((short)u0.w) + b2f((short)u1.w)) * inv);
}

// ---------------------------------------------------------------------------
// Kernel 3a (R7): register-direct GEMM (flatmm-style). NO LDS, NO barriers.
// Fragments loaded straight from L2: lane reads A[row][k0+quad*8..+8] (16B,
// wave covers exactly 16 full 64B lines per fragment - line-efficient).
// Register ping-pong gives one k-step of load-ahead; no sync anywhere, so
// compiler + 16 waves/CU hide L2 latency. Removes the 2-phase LDS
// structure's MfmaUtil~20% ceiling (R4/R6 post-mortems).
// ---------------------------------------------------------------------------
__global__ __launch_bounds__(256) void gemm_gelu(const unsigned short* __restrict__ A,
        const unsigned short* __restrict__ Bt, const float* __restrict__ bias,
        unsigned short* __restrict__ C, int M, int N, int Kd) {
    const int tid = threadIdx.x;
    const int w = tid >> 6, lane = tid & 63;
    const int l15 = lane & 15, quad = lane >> 4;
    const int wm = w >> 1, wn = w & 1;
    const int bn = blockIdx.x, bm = blockIdx.y;
    f32x4 acc[4][4] = {};

    const unsigned short* ap[4];
    const unsigned short* bp[4];
    #pragma unroll
    for (int mt = 0; mt < 4; ++mt)
        ap[mt] = A + (long)(bm*128 + wm*64 + mt*16 + l15)*Kd + quad*8;
    #pragma unroll
    for (int nt = 0; nt < 4; ++nt)
        bp[nt] = Bt + (long)(bn*128 + wn*64 + nt*16 + l15)*Kd + quad*8;

    const int NT = Kd >> 5;   // 32-wide k-steps; all call sites have NT even
    s16x8 afA[4], bfA[4], afB[4], bfB[4];
    #pragma unroll
    for (int i = 0; i < 4; ++i) {
        afA[i] = *(const s16x8*)(ap[i]);
        bfA[i] = *(const s16x8*)(bp[i]);
    }
    for (int t = 0; t < NT; t += 2) {
        const int k1 = (t + 1) * 32;
        #pragma unroll
        for (int i = 0; i < 4; ++i) {
            afB[i] = *(const s16x8*)(ap[i] + k1);
            bfB[i] = *(const s16x8*)(bp[i] + k1);
        }
        #pragma unroll
        for (int mt = 0; mt < 4; ++mt)
            #pragma unroll
            for (int nt = 0; nt < 4; ++nt)
                acc[mt][nt] = mfma16(afA[mt], bfA[nt], acc[mt][nt]);
        const int k2 = (t + 2 < NT) ? (t + 2) * 32 : 0;   // tail: dummy reload, unused
        #pragma unroll
        for (int i = 0; i < 4; ++i) {
            afA[i] = *(const s16x8*)(ap[i] + k2);
            bfA[i] = *(const s16x8*)(bp[i] + k2);
        }
        #pragma unroll
        for (int mt = 0; mt < 4; ++mt)
            #pragma unroll
            for (int nt = 0; nt < 4; ++nt)
                acc[mt][nt] = mfma16(afB[mt], bfB[nt], acc[mt][nt]);
    }

    #pragma unroll
    for (int mt = 0; mt < 4; ++mt) {
        const int row0 = bm*128 + wm*64 + mt*16 + quad*4;
        #pragma unroll
        for (int nt = 0; nt < 4; ++nt) {
            const int col = bn*128 + wn*64 + nt*16 + l15;
            const float bv = bias[col];
            #pragma unroll
            for (int r = 0; r < 4; ++r) {
                float v = acc[mt][nt][r] + bv;
                v = 0.5f * v * (1.f + erff(v * 0.70710678118654752440f));
                C[(long)(row0 + r)*N + col] = f2b(v);
            }
        }
    }
}

// ---------------------------------------------------------------------------
// Kernel 3b (R7): split-K GEMM, register-direct (same structure as 3a).
// ---------------------------------------------------------------------------
__global__ __launch_bounds__(256) void gemm_splitk(const unsigned short* __restrict__ A,
        const unsigned short* __restrict__ Bt, P4 parts, int M, int N, int Kd, int Ks) {
    const int tid = threadIdx.x;
    const int w = tid >> 6, lane = tid & 63;
    const int l15 = lane & 15, quad = lane >> 4;
    const int wm = w >> 1, wn = w & 1;
    const int bn = blockIdx.x, bm = blockIdx.y, s = blockIdx.z;
    f32x4 acc[4][4] = {};
    const int k0 = s * Ks;

    const unsigned short* ap[4];
    const unsigned short* bp[4];
    #pragma unroll
    for (int mt = 0; mt < 4; ++mt)
        ap[mt] = A + (long)(bm*128 + wm*64 + mt*16 + l15)*Kd + k0 + quad*8;
    #pragma unroll
    for (int nt = 0; nt < 4; ++nt)
        bp[nt] = Bt + (long)(bn*128 + wn*64 + nt*16 + l15)*Kd + k0 + quad*8;

    const int NT = Ks >> 5;   // even at all call sites (16/32/64)
    s16x8 afA[4], bfA[4], afB[4], bfB[4];
    #pragma unroll
    for (int i = 0; i < 4; ++i) {
        afA[i] = *(const s16x8*)(ap[i]);
        bfA[i] = *(const s16x8*)(bp[i]);
    }
    for (int t = 0; t < NT; t += 2) {
        const int k1 = (t + 1) * 32;
        #pragma unroll
        for (int i = 0; i < 4; ++i) {
            afB[i] = *(const s16x8*)(ap[i] + k1);
            bfB[i] = *(const s16x8*)(bp[i] + k1);
        }
        #pragma unroll
        for (int mt = 0; mt < 4; ++mt)
            #pragma unroll
            for (int nt = 0; nt < 4; ++nt)
                acc[mt][nt] = mfma16(afA[mt], bfA[nt], acc[mt][nt]);
        const int k2 = (t + 2 < NT) ? (t + 2) * 32 : 0;
        #pragma unroll
        for (int i = 0; i < 4; ++i) {
            afA[i] = *(const s16x8*)(ap[i] + k2);
            bfA[i] = *(const s16x8*)(bp[i] + k2);
        }
        #pragma unroll
        for (int mt = 0; mt < 4; ++mt)
            #pragma unroll
            for (int nt = 0; nt < 4; ++nt)
                acc[mt][nt] = mfma16(afB[mt], bfB[nt], acc[mt][nt]);
    }

    unsigned short* Cp = parts.p[s];
    #pragma unroll
    for (int mt = 0; mt < 4; ++mt) {
        const int row0 = bm*128 + wm*64 + mt*16 + quad*4;
        #pragma unroll
        for (int nt = 0; nt < 4; ++nt) {
            const int col = bn*128 + wn*64 + nt*16 + l15;
            #pragma unroll
            for (int r = 0; r < 4; ++r)
                Cp[(long)(row0 + r)*N + col] = f2b(acc[mt][nt][r]);
        }
    }
}

// ---------------------------------------------------------------------------
// Kernel 4: out = LayerNorm(xa + sum(partials) [+ addb]) * g + b
// XBF: xa is bf16 (residual chain kept in bf16). Outputs optional.
// ---------------------------------------------------------------------------
template <int P, int XBF>
__global__ __launch_bounds__(256) void ln_kernel(const void* __restrict__ xa,
        P4 parts, const float* __restrict__ addb, const float* __restrict__ g,
        const float* __restrict__ bia, float* __restrict__ out,
        unsigned short* __restrict__ outb) {
    const int row = blockIdx.x;
    const int tid = threadIdx.x;
    float4 v;
    if (XBF) {
        const ushort4 u = ((const ushort4*)xa)[(long)row * (EMB/4) + tid];
        v.x = b2f((short)u.x); v.y = b2f((short)u.y);
        v.z = b2f((short)u.z); v.w = b2f((short)u.w);
    } else {
        v = ((const float4*)xa)[(long)row * (EMB/4) + tid];
    }
    #pragma unroll
    for (int p = 0; p < P; ++p) {
        const ushort4 u = ((const ushort4*)(parts.p[p] + (long)row * EMB))[tid];
        v.x += b2f((short)u.x); v.y += b2f((short)u.y);
        v.z += b2f((short)u.z); v.w += b2f((short)u.w);
    }
    if (addb) {
        const float4 ab = ((const float4*)addb)[tid];
        v.x += ab.x; v.y += ab.y; v.z += ab.z; v.w += ab.w;
    }
    float s = v.x + v.y + v.z + v.w;
    float ss = v.x * v.x + v.y * v.y + v.z * v.z + v.w * v.w;
    #pragma unroll
    for (int off = 32; off > 0; off >>= 1) {
        s += __shfl_down(s, off, 64);
        ss += __shfl_down(ss, off, 64);
    }
    __shared__ float ls[4], lss[4];
    __shared__ float mean_s, rstd_s;
    const int wid = tid >> 6, lane = tid & 63;
    if (lane == 0) { ls[wid] = s; lss[wid] = ss; }
    __syncthreads();
    if (tid == 0) {
        const float S0 = ls[0] + ls[1] + ls[2] + ls[3];
        const float S2 = lss[0] + lss[1] + lss[2] + lss[3];
        const float mean = S0 * (1.f / EMB);
        const float var = S2 * (1.f / EMB) - mean * mean;
        mean_s = mean;
        rstd_s = rsqrtf(var + 1e-5f);
    }
    __syncthreads();
    const float mean = mean_s, rstd = rstd_s;
    const float4 gg = ((const float4*)g)[tid];
    const float4 bb = ((const float4*)bia)[tid];
    float4 o;
    o.x = (v.x - mean) * rstd * gg.x + bb.x;
    o.y = (v.y - mean) * rstd * gg.y + bb.y;
    o.z = (v.z - mean) * rstd * gg.z + bb.z;
    o.w = (v.w - mean) * rstd * gg.w + bb.w;
    if (out) ((float4*)(out + (long)row * EMB))[tid] = o;
    if (outb) {
        unsigned short* ob = outb + (long)row * EMB + tid * 4;
        ob[0] = f2b(o.x); ob[1] = f2b(o.y); ob[2] = f2b(o.z); ob[3] = f2b(o.w);
    }
}

// ---------------------------------------------------------------------------
// Kernel 5: all weight transposes fused into one dispatch. 32x32 fp32->bf16.
// ---------------------------------------------------------------------------
__global__ __launch_bounds__(256) void transp_all(const float* __restrict__ Wp,
        const float* __restrict__ W1, const float* __restrict__ W2,
        const float* __restrict__ Wq, unsigned short* __restrict__ Wpt,
        unsigned short* __restrict__ W1t, unsigned short* __restrict__ W2t,
        unsigned short* __restrict__ Wqt) {
    int id = blockIdx.x;
    const float* W; unsigned short* Wt; int Kd, N, ntx;
    if (id < 1024)      {            W = Wp; Wt = Wpt; Kd = 1024; N = 1024; ntx = 32; }
    else if (id < 5120) { id -= 1024; W = W1; Wt = W1t; Kd = 1024; N = 4096; ntx = 128; }
    else if (id < 9216) { id -= 5120; W = W2; Wt = W2t; Kd = 4096; N = 1024; ntx = 32; }
    else                { id -= 9216; W = Wq; Wt = Wqt; Kd = 64;   N = 192;  ntx = 6;  }
    __shared__ float Ts[32][33];
    const int tid = threadIdx.x;
    const int n0 = (id % ntx) * 32, k0 = (id / ntx) * 32;
    const int r = tid >> 3, c4 = (tid & 7) * 4;
    const float4 v = *(const float4*)&W[(long)(k0 + r) * N + n0 + c4];
    Ts[r][c4] = v.x; Ts[r][c4 + 1] = v.y; Ts[r][c4 + 2] = v.z; Ts[r][c4 + 3] = v.w;
    __syncthreads();
    #pragma unroll
    for (int i = 0; i < 4; ++i)
        Wt[(long)(n0 + r) * Kd + k0 + c4 + i] = f2b(Ts[c4 + i][r]);
}

// ---------------------------------------------------------------------------
extern "C" void kernel_launch(void* const* d_in, const int* in_sizes, int n_in,
                              void* d_out, int out_size, void* d_ws, size_t ws_size,
                              hipStream_t stream) {
    (void)in_sizes; (void)n_in; (void)out_size;
    const float* x     = (const float*)d_in[0];
    const float* Wkqv  = (const float*)d_in[1];
    const float* Wproj = (const float*)d_in[2];
    const float* g1    = (const float*)d_in[3];
    const float* b1    = (const float*)d_in[4];
    const float* W1    = (const float*)d_in[5];
    const float* bff1  = (const float*)d_in[6];
    const float* W2    = (const float*)d_in[7];
    const float* bff2  = (const float*)d_in[8];
    const float* g2    = (const float*)d_in[9];
    const float* b2    = (const float*)d_in[10];
    float* out = (float*)d_out;
    char* ws = (char*)d_ws;

    // layout (MB offsets), 90 MB base envelope (proven in prior rounds):
    //  0.. 8 Qb -> x1b     8..40 Kb/Vb/resb -> hb
    // 40..48 VT (dead after attn) -> mp0/fp0   48..56 mp1/fp1
    // 48..64 Opb (attn partials, dead after combine; mp1 overwrites later)
    // 64..64.5 lpb   72..74 Wpt  74..82 W1t  82..90 W2t  90 Wqt
    // big path (ws >= 108 MB): fp2 at 91, fp3 at 99
    const size_t MB = 1u << 20;
    unsigned short* Qb   = (unsigned short*)(ws + 0 * MB);
    unsigned short* Kb   = (unsigned short*)(ws + 8 * MB);
    unsigned short* Vb   = (unsigned short*)(ws + 16 * MB);
    unsigned short* resb = (unsigned short*)(ws + 24 * MB);
    unsigned short* hb   = (unsigned short*)(ws + 8 * MB);    // 32 MB (8..40)
    unsigned short* VTb  = (unsigned short*)(ws + 40 * MB);   // 8 MB
    unsigned short* mp0  = (unsigned short*)(ws + 40 * MB);
    unsigned short* mp1  = (unsigned short*)(ws + 48 * MB);
    unsigned short* Opb  = (unsigned short*)(ws + 48 * MB);   // 16 MB (48..64)
    float*          lpb  = (float*)         (ws + 64 * MB);   // 512 KB
    unsigned short* x1b  = Qb;
    unsigned short* Wpt  = (unsigned short*)(ws + 72 * MB);
    unsigned short* W1t  = (unsigned short*)(ws + 74 * MB);
    unsigned short* W2t  = (unsigned short*)(ws + 82 * MB);
    unsigned short* Wqt  = (unsigned short*)(ws + 90 * MB);
    unsigned short* fp2  = (unsigned short*)(ws + 91 * MB);
    unsigned short* fp3  = (unsigned short*)(ws + 99 * MB);
    const bool big = ws_size >= 108 * MB;   // constant per-process -> graph-safe

    // weight prep (single fused dispatch; every call - no persistent state)
    transp_all<<<dim3(9228), 256, 0, stream>>>(Wproj, W1, W2, Wkqv, Wpt, W1t, W2t, Wqt);

    // 1. kqv projection (MFMA, bf16 out, x-row order) + V transpose
    kqv_kernel<<<dim3(ROWS/128), 256, 0, stream>>>(x, Wqt, Kb, Qb, Vb);
    vt_kernel<<<dim3(T_/64, B_*H_), 256, 0, stream>>>(Vb, VTb);
    // 2. flash attention, 4-wave blocks, kv-split=2 -> 1024 blocks;
    //    partials combined exactly (no online max -> sums add)
    attn_kernel<<<dim3(512, 2), 256, 0, stream>>>(Qb, Kb, VTb, Opb, lpb);
    attn_combine<<<dim3(ROWS*16/256), 256, 0, stream>>>(Opb, lpb, resb);
    // 3. mha = res @ Wproj, split-K=2 (bf16 partials; summed in LN1)
    P4 mp; mp.p[0] = mp0; mp.p[1] = mp1; mp.p[2] = nullptr; mp.p[3] = nullptr;
    gemm_splitk<<<dim3(EMB/128, BT/128, 2), 256, 0, stream>>>(resb, Wpt, mp, BT, EMB, EMB, EMB/2);
    // 4. x1 = LN(x + mp0 + mp1)  (bf16 only)
    ln_kernel<2, 0><<<dim3(BT), 256, 0, stream>>>(x, mp, nullptr, g1, b1, nullptr, x1b);
    // 5. h = gelu(x1 @ W1 + bff1) (bf16 out)
    gemm_gelu<<<dim3(FF/128, BT/128), 256, 0, stream>>>(x1b, W1t, bff1, hb, BT, FF, EMB);
    // 6+7. ff = h @ W2 (split-K), then out = LN(x1b + sum(fp) + bff2)
    if (big) {
        P4 fp; fp.p[0] = mp0; fp.p[1] = mp1; fp.p[2] = fp2; fp.p[3] = fp3;
        gemm_splitk<<<dim3(EMB/128, BT/128, 4), 256, 0, stream>>>(hb, W2t, fp, BT, EMB, FF, FF/4);
        ln_kernel<4, 1><<<dim3(BT), 256, 0, stream>>>(x1b, fp, bff2, g2, b2, out, nullptr);
    } else {
        P4 fp; fp.p[0] = mp0; fp.p[1] = mp1; fp.p[2] = nullptr; fp.p[3] = nullptr;
        gemm_splitk<<<dim3(EMB/128, BT/128, 2), 256, 0, stream>>>(hb, W2t, fp, BT, EMB, FF, FF/2);
        ln_kernel<2, 1><<<dim3(BT), 256, 0, stream>>>(x1b, fp, bff2, g2, b2, out, nullptr);
    }
}

// Round 9
// 342.422 us; speedup vs baseline: 1.4313x; 1.4313x over previous
//
#include <hip/hip_runtime.h>
#include <hip/hip_bf16.h>
#include <math.h>

#define B_ 2
#define T_ 2048
#define H_ 16
#define S_ 64
#define EMB 1024
#define FF 4096
#define BT (B_*T_)        // 4096 rows
#define ROWS (B_*T_*H_)   // 65536

typedef __attribute__((ext_vector_type(8))) short s16x8;   // 8 bf16 (4 VGPRs)
typedef __attribute__((ext_vector_type(4))) float f32x4;   // MFMA C/D

struct P4 { unsigned short* p[4]; };   // partial-sum pointers (bf16)

__device__ __forceinline__ unsigned short f2b(float f) {
    return __builtin_bit_cast(unsigned short, __float2bfloat16(f));
}
__device__ __forceinline__ float b2f(short u) {
    return __builtin_bit_cast(float, ((unsigned int)(unsigned short)u) << 16);
}

// async global->LDS, 16B per lane (LDS dest = wave-uniform base + lane*16;
// GLOBAL address may be fully per-lane - only the LDS side is constrained)
__device__ __forceinline__ void gl_lds16(const void* g, void* l) {
    __builtin_amdgcn_global_load_lds(
        (const __attribute__((address_space(1))) void*)g,
        (__attribute__((address_space(3))) void*)l, 16, 0, 0);
}

__device__ __forceinline__ f32x4 mfma16(s16x8 a, s16x8 b, f32x4 c) {
    return __builtin_amdgcn_mfma_f32_16x16x32_bf16(a, b, c, 0, 0, 0);
}

// s_waitcnt simm16 (gfx9): vmcnt[3:0]|hi[15:14], expcnt[6:4], lgkmcnt[11:8]
#define WAIT_VM4 0x0F74   // vmcnt(4)
#define WAIT_VM2 0x0F72   // vmcnt(2)
#define WAIT_VM0 0x0F70   // vmcnt(0)

// R6 LDS bank-conflict swizzle (rule #21: linear gl_lds dest + inverse-
// permuted GLOBAL source + same-permuted read). Tiles are [row][64B]:
// read slot was (4*(row&1)+quad)&7 -> 8 lanes/slot (8-way conflict).
// chunk' = chunk ^ ((row>>1)&3) spreads 16 l15-lanes over all 8 slots
// (2/slot = free). Staged row = c*16 + (lane>>2) -> key = (lane>>3)&3.

// ---------------------------------------------------------------------------
// Kernel 1: kqv, MFMA version. x [ROWS][64] fp32, Wqt [192][64] bf16.
// Outputs K,Q,V bf16 in x-row order: [ (b*T+t)*H+h ][64].
// ---------------------------------------------------------------------------
__global__ __launch_bounds__(256) void kqv_kernel(const float* __restrict__ x,
        const unsigned short* __restrict__ Wqt, unsigned short* __restrict__ K,
        unsigned short* __restrict__ Q, unsigned short* __restrict__ V) {
    const int tid = threadIdx.x;
    const int w = tid >> 6, lane = tid & 63;
    const int l15 = lane & 15, quad = lane >> 4;
    const long r0 = (long)blockIdx.x * 128 + w * 32;

    s16x8 af[2][2];
    #pragma unroll
    for (int mt = 0; mt < 2; ++mt)
        #pragma unroll
        for (int ks = 0; ks < 2; ++ks) {
            const float* xp = x + (r0 + mt*16 + l15) * 64 + ks*32 + quad*8;
            const float4 v0 = *(const float4*)xp;
            const float4 v1 = *(const float4*)(xp + 4);
            s16x8 a;
            a[0] = (short)f2b(v0.x); a[1] = (short)f2b(v0.y);
            a[2] = (short)f2b(v0.z); a[3] = (short)f2b(v0.w);
            a[4] = (short)f2b(v1.x); a[5] = (short)f2b(v1.y);
            a[6] = (short)f2b(v1.z); a[7] = (short)f2b(v1.w);
            af[mt][ks] = a;
        }

    #pragma unroll
    for (int nt = 0; nt < 12; ++nt) {
        const s16x8 b0 = *(const s16x8*)&Wqt[(nt*16 + l15)*64 + quad*8];
        const s16x8 b1 = *(const s16x8*)&Wqt[(nt*16 + l15)*64 + 32 + quad*8];
        f32x4 acc[2] = {};
        #pragma unroll
        for (int mt = 0; mt < 2; ++mt) {
            acc[mt] = mfma16(af[mt][0], b0, acc[mt]);
            acc[mt] = mfma16(af[mt][1], b1, acc[mt]);
        }
        unsigned short* dst = (nt < 4) ? K : (nt < 8) ? Q : V;
        const int c0 = (nt & 3) * 16 + l15;
        #pragma unroll
        for (int mt = 0; mt < 2; ++mt)
            #pragma unroll
            for (int r = 0; r < 4; ++r)
                dst[(r0 + mt*16 + quad*4 + r) * 64 + c0] = f2b(acc[mt][r]);
    }
}

// ---------------------------------------------------------------------------
// Kernel 1b: V [ (b,t,h) ][d] -> VT [bh][d][t]  (64x64 tiles per (b,h))
// ---------------------------------------------------------------------------
__global__ __launch_bounds__(256) void vt_kernel(const unsigned short* __restrict__ V,
        unsigned short* __restrict__ VT) {
    __shared__ unsigned short Ts[64][72];
    const int tid = threadIdx.x;
    const int tt = blockIdx.x, bh = blockIdx.y;
    const int b = bh >> 4, h = bh & 15;
    const long vbase = ((long)b * (T_*H_) + h) * 64;   // + t*1024 + d
    #pragma unroll
    for (int i = 0; i < 2; ++i) {
        const int id = i * 256 + tid;          // 0..511
        const int tr = id >> 3, dc = (id & 7) * 8;
        const s16x8 v = *(const s16x8*)&V[vbase + (long)(tt*64 + tr)*1024 + dc];
        *(s16x8*)&Ts[tr][dc] = v;
    }
    __syncthreads();
    #pragma unroll
    for (int i = 0; i < 2; ++i) {
        const int id = i * 256 + tid;
        const int d = id >> 3, tc = (id & 7) * 8;
        s16x8 o;
        #pragma unroll
        for (int j = 0; j < 8; ++j) o[j] = (short)Ts[tc + j][d];
        *(s16x8*)&VT[((long)bh*64 + d)*2048 + tt*64 + tc] = o;
    }
}

// ---------------------------------------------------------------------------
// Kernel 2 (R6): flash attention, 4-wave blocks, kv-split=2, swizzled LDS.
// K/V LDS reads conflict-free via source-side swizzle + XOR'd read chunk.
// Ps pad 40 for 16B-aligned conflict-free P reloads.
// ---------------------------------------------------------------------------
__global__ __launch_bounds__(256) void attn_kernel(const unsigned short* __restrict__ Q,
        const unsigned short* __restrict__ K, const unsigned short* __restrict__ VT,
        unsigned short* __restrict__ Op, float* __restrict__ lp) {
    __shared__ __align__(16) unsigned short Kbuf[2][2][32*32];  // [buf][dhalf][j][d32]
    __shared__ __align__(16) unsigned short Vbuf[2][64*32];     // [buf][d][t32]
    __shared__ __align__(16) unsigned short Ps[4][32*40];       // per-wave [q][j], pad 40
    const int tid = threadIdx.x;
    const int wid = tid >> 6, lane = tid & 63;
    const int l15 = lane & 15, quad = lane >> 4;
    const int bid = blockIdx.x;
    const int s = blockIdx.y;                 // kv-split index (0,1)
    const int qg = bid & 15, bh = bid >> 4;   // 16 q-groups consecutive -> L2 locality per bh
    const long base = ((long)(bh >> 4) * (T_*H_) + (bh & 15)) * 64;  // x-row order
    const unsigned short* Qp = Q + base;
    const unsigned short* Kp = K + base;
    const unsigned short* Vp = VT + (long)bh * 64 * 2048;   // [d][t]
    const int q0 = qg * 128 + wid * 32;
    const int kt0 = s * 32;                   // 32 key-tiles per split
    unsigned short* ps = &Ps[wid][0];
    const int rk = (l15 >> 1) & 3;            // read-side swizzle key
    const int sc8 = ((lane & 3) ^ ((lane >> 3) & 3)) * 8;   // staged source chunk

    // Q fragments (B-operand layout), pre-scaled by 1/8 (exact in bf16)
    s16x8 qf[2][2];
    #pragma unroll
    for (int qq = 0; qq < 2; ++qq)
        #pragma unroll
        for (int ks = 0; ks < 2; ++ks) {
            const s16x8 raw = *(const s16x8*)&Qp[(long)(q0 + qq*16 + l15)*1024 + ks*32 + quad*8];
            s16x8 q;
            #pragma unroll
            for (int j = 0; j < 8; ++j) q[j] = (short)f2b(b2f(raw[j]) * 0.125f);
            qf[qq][ks] = q;
        }

    s16x8 onef;
    #pragma unroll
    for (int j = 0; j < 8; ++j) onef[j] = (short)0x3F80;   // bf16 1.0

    f32x4 oacc[2][4] = {};
    f32x4 lacc[2] = {};

    const int j16 = lane >> 2;           // staging row within 16-row call

    // stage: 8 x 1KB gl_lds calls split across 4 waves (2 per wave).
    // Global source column carries the inverse swizzle (sc8).
    auto stage = [&](int bufi, int kt) {
        char* kl = (char*)&Kbuf[bufi][0][0];
        char* vl = (char*)&Vbuf[bufi][0];
        const unsigned short* kg = Kp + (long)(kt*32) * 1024;
        const unsigned short* vg = Vp + kt*32 + sc8;
        switch (wid) {
        case 0:
            gl_lds16(kg + (long)j16*1024 + sc8,           kl +    0 + lane*16);
            gl_lds16(kg + (long)(j16+16)*1024 + sc8,      kl + 1024 + lane*16);
            break;
        case 1:
            gl_lds16(kg + (long)j16*1024 + 32 + sc8,      kl + 2048 + lane*16);
            gl_lds16(kg + (long)(j16+16)*1024 + 32 + sc8, kl + 3072 + lane*16);
            break;
        case 2:
            gl_lds16(vg + (long)(j16     )*2048, vl +    0 + lane*16);
            gl_lds16(vg + (long)(j16 + 16)*2048, vl + 1024 + lane*16);
            break;
        default:
            gl_lds16(vg + (long)(j16 + 32)*2048, vl + 2048 + lane*16);
            gl_lds16(vg + (long)(j16 + 48)*2048, vl + 3072 + lane*16);
            break;
        }
    };

    auto compute = [&](int bufi) {
        // S^T = K Q^T : A=K from LDS (swizzled read), B=Q regs
        f32x4 sT[2][2] = {};
        #pragma unroll
        for (int ks = 0; ks < 2; ++ks)
            #pragma unroll
            for (int jt = 0; jt < 2; ++jt) {
                const s16x8 kf = *(const s16x8*)&Kbuf[bufi][ks][(jt*16 + l15)*32 + (quad ^ rk)*8];
                sT[jt][0] = mfma16(kf, qf[0][ks], sT[jt][0]);
                sT[jt][1] = mfma16(kf, qf[1][ks], sT[jt][1]);
            }
        // P = exp(S): pack 4 j-consecutive values -> b64 store to ps[q][j]
        #pragma unroll
        for (int jt = 0; jt < 2; ++jt)
            #pragma unroll
            for (int qq = 0; qq < 2; ++qq) {
                uint2 pk;
                pk.x = (unsigned int)f2b(__expf(sT[jt][qq][0]))
                     | ((unsigned int)f2b(__expf(sT[jt][qq][1])) << 16);
                pk.y = (unsigned int)f2b(__expf(sT[jt][qq][2]))
                     | ((unsigned int)f2b(__expf(sT[jt][qq][3])) << 16);
                *(uint2*)&ps[(qq*16 + l15)*40 + jt*16 + quad*4] = pk;
            }
        // O += P V ; l += P 1   (wave-private LDS, DS in-order per wave)
        s16x8 pf[2];
        #pragma unroll
        for (int qq = 0; qq < 2; ++qq) {
            pf[qq] = *(const s16x8*)&ps[(qq*16 + l15)*40 + quad*8];
            lacc[qq] = mfma16(pf[qq], onef, lacc[qq]);
        }
        #pragma unroll
        for (int nt = 0; nt < 4; ++nt) {
            const s16x8 vf = *(const s16x8*)&Vbuf[bufi][(nt*16 + l15)*32 + (quad ^ rk)*8];
            oacc[0][nt] = mfma16(pf[0], vf, oacc[0][nt]);
            oacc[1][nt] = mfma16(pf[1], vf, oacc[1][nt]);
        }
    };

    stage(0, kt0);
    for (int kt = 0; kt < 31; ++kt) {
        stage((kt + 1) & 1, kt0 + kt + 1);           // prefetch next tile
        __builtin_amdgcn_s_waitcnt(WAIT_VM2);        // own 2 loads of tile kt landed
        __builtin_amdgcn_s_barrier();                // all waves' tile-kt loads landed
        __builtin_amdgcn_sched_barrier(0);
        compute(kt & 1);
        __builtin_amdgcn_s_barrier();                // buf kt&1 readers done before t+2 overwrite
        __builtin_amdgcn_sched_barrier(0);
    }
    __builtin_amdgcn_s_waitcnt(WAIT_VM0);
    __builtin_amdgcn_s_barrier();
    __builtin_amdgcn_sched_barrier(0);
    compute(1);   // kt = 31 (31 & 1 = 1)

    // epilogue: unnormalized O partial (bf16) + l partial (fp32).
    // Op layout [s][bh][t][d], lp layout [s][bh][t]; combined later.
    unsigned short* op = Op + ((long)s * 32 + bh) * 2048 * 64;
    float* lrow = lp + ((long)s * 32 + bh) * 2048;
    #pragma unroll
    for (int qq = 0; qq < 2; ++qq)
        #pragma unroll
        for (int r = 0; r < 4; ++r) {
            const int t = q0 + qq*16 + quad*4 + r;
            if (l15 == 0) lrow[t] = lacc[qq][r];
            #pragma unroll
            for (int nt = 0; nt < 4; ++nt)
                op[(long)t*64 + nt*16 + l15] = f2b(oacc[qq][nt][r]);
        }
}

// ---------------------------------------------------------------------------
// Kernel 2b (R3): combine kv-split partials: res = (O0+O1)/(l0+l1),
// written in x-row order [(b*T+t)*EMB + h*64 + d] for the Wproj GEMM.
// ---------------------------------------------------------------------------
__global__ __launch_bounds__(256) void attn_combine(const unsigned short* __restrict__ Op,
        const float* __restrict__ lp, unsigned short* __restrict__ res) {
    const int gid = blockIdx.x * 256 + threadIdx.x;
    const int row = gid >> 4;              // bh*2048 + t
    const int c4 = (gid & 15) * 4;
    const int bh = row >> 11, t = row & 2047;
    const int b = bh >> 4, h = bh & 15;
    const float inv = 1.f / (lp[row] + lp[ROWS + row]);
    const ushort4 u0 = *(const ushort4*)&Op[(long)row * 64 + c4];
    const ushort4 u1 = *(const ushort4*)&Op[((long)ROWS + row) * 64 + c4];
    unsigned short* r = res + ((long)(b*T_ + t)) * EMB + h*64 + c4;
    r[0] = f2b((b2f((short)u0.x) + b2f((short)u1.x)) * inv);
    r[1] = f2b((b2f((short)u0.y) + b2f((short)u1.y)) * inv);
    r[2] = f2b((b2f((short)u0.z) + b2f((short)u1.z)) * inv);
    r[3] = f2b((b2f((short)u0.w) + b2f((short)u1.w)) * inv);
}

// ---------------------------------------------------------------------------
// Kernel 3a (R8): bf16 MFMA GEMM, 3-buffer single-barrier pipeline.
// Per iter t: vmcnt(4|0) [own tile-t loads landed; t+1's in flight] ->
// s_barrier [ALL waves' t-loads landed AND all finished reading t-1,
// since that read precedes their barrier arrival] -> stage(t+2 into
// buf (t+2)%3 == (t-1)%3, now safe) -> ds_read+MFMA(buf t%3).
// One barrier/iter (R6 had two) + one extra tile of prefetch depth.
// LDS swizzle from R6 kept (conflict-free ds_read_b128).
// ---------------------------------------------------------------------------
__global__ __launch_bounds__(256) void gemm_gelu(const unsigned short* __restrict__ A,
        const unsigned short* __restrict__ Bt, const float* __restrict__ bias,
        unsigned short* __restrict__ C, int M, int N, int Kd) {
    __shared__ __align__(16) unsigned short As[3][128 * 32];
    __shared__ __align__(16) unsigned short Bs[3][128 * 32];
    const int tid = threadIdx.x;
    const int w = tid >> 6, lane = tid & 63;
    const int l15 = lane & 15, quad = lane >> 4;
    const int wm = w >> 1, wn = w & 1;
    const int bn = blockIdx.x, bm = blockIdx.y;
    const int sr = lane >> 2;
    const int sskq = (lane & 3) ^ ((lane >> 3) & 3);   // swizzled source chunk
    const int rk = (l15 >> 1) & 3;                     // read-side key
    f32x4 acc[4][4] = {};
    const long arow = (long)(bm*128 + w*32 + sr);
    const long brow = (long)(bn*128 + w*32 + sr);

    auto stage = [&](int bi, int kt) {
        char* as = (char*)&As[bi][0];
        char* bs = (char*)&Bs[bi][0];
        gl_lds16(A  + (arow     )*Kd + kt + sskq*8, as + (w*32     )*64 + lane*16);
        gl_lds16(A  + (arow + 16)*Kd + kt + sskq*8, as + (w*32 + 16)*64 + lane*16);
        gl_lds16(Bt + (brow     )*Kd + kt + sskq*8, bs + (w*32     )*64 + lane*16);
        gl_lds16(Bt + (brow + 16)*Kd + kt + sskq*8, bs + (w*32 + 16)*64 + lane*16);
    };

    const int NT = Kd >> 5;
    stage(0, 0);
    stage(1, 32);
    int cur = 0;
    for (int t = 0; t < NT; ++t) {
        if (t + 1 < NT) __builtin_amdgcn_s_waitcnt(WAIT_VM4);  // tile t landed (t+1 newest 4)
        else            __builtin_amdgcn_s_waitcnt(WAIT_VM0);  // last tile: drain
        __builtin_amdgcn_s_barrier();
        __builtin_amdgcn_sched_barrier(0);
        int nxt = cur + 2; if (nxt >= 3) nxt -= 3;
        if (t + 2 < NT) stage(nxt, (t + 2) * 32);    // overwrites buf (t-1)%3: readers done
        s16x8 af[4], bf[4];
        #pragma unroll
        for (int mt = 0; mt < 4; ++mt)
            af[mt] = *(const s16x8*)&As[cur][(wm*64 + mt*16 + l15)*32 + (quad ^ rk)*8];
        #pragma unroll
        for (int nt = 0; nt < 4; ++nt)
            bf[nt] = *(const s16x8*)&Bs[cur][(wn*64 + nt*16 + l15)*32 + (quad ^ rk)*8];
        #pragma unroll
        for (int mt = 0; mt < 4; ++mt)
            #pragma unroll
            for (int nt = 0; nt < 4; ++nt)
                acc[mt][nt] = mfma16(af[mt], bf[nt], acc[mt][nt]);
        cur = cur + 1; if (cur >= 3) cur -= 3;
    }

    #pragma unroll
    for (int mt = 0; mt < 4; ++mt) {
        const int row0 = bm*128 + wm*64 + mt*16 + quad*4;
        #pragma unroll
        for (int nt = 0; nt < 4; ++nt) {
            const int col = bn*128 + wn*64 + nt*16 + l15;
            const float bv = bias[col];
            #pragma unroll
            for (int r = 0; r < 4; ++r) {
                float v = acc[mt][nt][r] + bv;
                v = 0.5f * v * (1.f + erff(v * 0.70710678118654752440f));
                C[(long)(row0 + r)*N + col] = f2b(v);
            }
        }
    }
}

// ---------------------------------------------------------------------------
// Kernel 3b (R8): split-K GEMM, same 3-buffer single-barrier pipeline.
// ---------------------------------------------------------------------------
__global__ __launch_bounds__(256) void gemm_splitk(const unsigned short* __restrict__ A,
        const unsigned short* __restrict__ Bt, P4 parts, int M, int N, int Kd, int Ks) {
    __shared__ __align__(16) unsigned short As[3][128 * 32];
    __shared__ __align__(16) unsigned short Bs[3][128 * 32];
    const int tid = threadIdx.x;
    const int w = tid >> 6, lane = tid & 63;
    const int l15 = lane & 15, quad = lane >> 4;
    const int wm = w >> 1, wn = w & 1;
    const int bn = blockIdx.x, bm = blockIdx.y, s = blockIdx.z;
    const int sr = lane >> 2;
    const int sskq = (lane & 3) ^ ((lane >> 3) & 3);
    const int rk = (l15 >> 1) & 3;
    f32x4 acc[4][4] = {};
    const long arow = (long)(bm*128 + w*32 + sr);
    const long brow = (long)(bn*128 + w*32 + sr);
    const int k0 = s * Ks;

    auto stage = [&](int bi, int kt) {
        char* as = (char*)&As[bi][0];
        char* bs = (char*)&Bs[bi][0];
        gl_lds16(A  + (arow     )*Kd + kt + sskq*8, as + (w*32     )*64 + lane*16);
        gl_lds16(A  + (arow + 16)*Kd + kt + sskq*8, as + (w*32 + 16)*64 + lane*16);
        gl_lds16(Bt + (brow     )*Kd + kt + sskq*8, bs + (w*32     )*64 + lane*16);
        gl_lds16(Bt + (brow + 16)*Kd + kt + sskq*8, bs + (w*32 + 16)*64 + lane*16);
    };

    const int NT = Ks >> 5;
    stage(0, k0);
    stage(1, k0 + 32);
    int cur = 0;
    for (int t = 0; t < NT; ++t) {
        if (t + 1 < NT) __builtin_amdgcn_s_waitcnt(WAIT_VM4);
        else            __builtin_amdgcn_s_waitcnt(WAIT_VM0);
        __builtin_amdgcn_s_barrier();
        __builtin_amdgcn_sched_barrier(0);
        int nxt = cur + 2; if (nxt >= 3) nxt -= 3;
        if (t + 2 < NT) stage(nxt, k0 + (t + 2) * 32);
        s16x8 af[4], bf[4];
        #pragma unroll
        for (int mt = 0; mt < 4; ++mt)
            af[mt] = *(const s16x8*)&As[cur][(wm*64 + mt*16 + l15)*32 + (quad ^ rk)*8];
        #pragma unroll
        for (int nt = 0; nt < 4; ++nt)
            bf[nt] = *(const s16x8*)&Bs[cur][(wn*64 + nt*16 + l15)*32 + (quad ^ rk)*8];
        #pragma unroll
        for (int mt = 0; mt < 4; ++mt)
            #pragma unroll
            for (int nt = 0; nt < 4; ++nt)
                acc[mt][nt] = mfma16(af[mt], bf[nt], acc[mt][nt]);
        cur = cur + 1; if (cur >= 3) cur -= 3;
    }

    unsigned short* Cp = parts.p[s];
    #pragma unroll
    for (int mt = 0; mt < 4; ++mt) {
        const int row0 = bm*128 + wm*64 + mt*16 + quad*4;
        #pragma unroll
        for (int nt = 0; nt < 4; ++nt) {
            const int col = bn*128 + wn*64 + nt*16 + l15;
            #pragma unroll
            for (int r = 0; r < 4; ++r)
                Cp[(long)(row0 + r)*N + col] = f2b(acc[mt][nt][r]);
        }
    }
}

// ---------------------------------------------------------------------------
// Kernel 4: out = LayerNorm(xa + sum(partials) [+ addb]) * g + b
// XBF: xa is bf16 (residual chain kept in bf16). Outputs optional.
// ---------------------------------------------------------------------------
template <int P, int XBF>
__global__ __launch_bounds__(256) void ln_kernel(const void* __restrict__ xa,
        P4 parts, const float* __restrict__ addb, const float* __restrict__ g,
        const float* __restrict__ bia, float* __restrict__ out,
        unsigned short* __restrict__ outb) {
    const int row = blockIdx.x;
    const int tid = threadIdx.x;
    float4 v;
    if (XBF) {
        const ushort4 u = ((const ushort4*)xa)[(long)row * (EMB/4) + tid];
        v.x = b2f((short)u.x); v.y = b2f((short)u.y);
        v.z = b2f((short)u.z); v.w = b2f((short)u.w);
    } else {
        v = ((const float4*)xa)[(long)row * (EMB/4) + tid];
    }
    #pragma unroll
    for (int p = 0; p < P; ++p) {
        const ushort4 u = ((const ushort4*)(parts.p[p] + (long)row * EMB))[tid];
        v.x += b2f((short)u.x); v.y += b2f((short)u.y);
        v.z += b2f((short)u.z); v.w += b2f((short)u.w);
    }
    if (addb) {
        const float4 ab = ((const float4*)addb)[tid];
        v.x += ab.x; v.y += ab.y; v.z += ab.z; v.w += ab.w;
    }
    float s = v.x + v.y + v.z + v.w;
    float ss = v.x * v.x + v.y * v.y + v.z * v.z + v.w * v.w;
    #pragma unroll
    for (int off = 32; off > 0; off >>= 1) {
        s += __shfl_down(s, off, 64);
        ss += __shfl_down(ss, off, 64);
    }
    __shared__ float ls[4], lss[4];
    __shared__ float mean_s, rstd_s;
    const int wid = tid >> 6, lane = tid & 63;
    if (lane == 0) { ls[wid] = s; lss[wid] = ss; }
    __syncthreads();
    if (tid == 0) {
        const float S0 = ls[0] + ls[1] + ls[2] + ls[3];
        const float S2 = lss[0] + lss[1] + lss[2] + lss[3];
        const float mean = S0 * (1.f / EMB);
        const float var = S2 * (1.f / EMB) - mean * mean;
        mean_s = mean;
        rstd_s = rsqrtf(var + 1e-5f);
    }
    __syncthreads();
    const float mean = mean_s, rstd = rstd_s;
    const float4 gg = ((const float4*)g)[tid];
    const float4 bb = ((const float4*)bia)[tid];
    float4 o;
    o.x = (v.x - mean) * rstd * gg.x + bb.x;
    o.y = (v.y - mean) * rstd * gg.y + bb.y;
    o.z = (v.z - mean) * rstd * gg.z + bb.z;
    o.w = (v.w - mean) * rstd * gg.w + bb.w;
    if (out) ((float4*)(out + (long)row * EMB))[tid] = o;
    if (outb) {
        unsigned short* ob = outb + (long)row * EMB + tid * 4;
        ob[0] = f2b(o.x); ob[1] = f2b(o.y); ob[2] = f2b(o.z); ob[3] = f2b(o.w);
    }
}

// ---------------------------------------------------------------------------
// Kernel 5: all weight transposes fused into one dispatch. 32x32 fp32->bf16.
// ---------------------------------------------------------------------------
__global__ __launch_bounds__(256) void transp_all(const float* __restrict__ Wp,
        const float* __restrict__ W1, const float* __restrict__ W2,
        const float* __restrict__ Wq, unsigned short* __restrict__ Wpt,
        unsigned short* __restrict__ W1t, unsigned short* __restrict__ W2t,
        unsigned short* __restrict__ Wqt) {
    int id = blockIdx.x;
    const float* W; unsigned short* Wt; int Kd, N, ntx;
    if (id < 1024)      {            W = Wp; Wt = Wpt; Kd = 1024; N = 1024; ntx = 32; }
    else if (id < 5120) { id -= 1024; W = W1; Wt = W1t; Kd = 1024; N = 4096; ntx = 128; }
    else if (id < 9216) { id -= 5120; W = W2; Wt = W2t; Kd = 4096; N = 1024; ntx = 32; }
    else                { id -= 9216; W = Wq; Wt = Wqt; Kd = 64;   N = 192;  ntx = 6;  }
    __shared__ float Ts[32][33];
    const int tid = threadIdx.x;
    const int n0 = (id % ntx) * 32, k0 = (id / ntx) * 32;
    const int r = tid >> 3, c4 = (tid & 7) * 4;
    const float4 v = *(const float4*)&W[(long)(k0 + r) * N + n0 + c4];
    Ts[r][c4] = v.x; Ts[r][c4 + 1] = v.y; Ts[r][c4 + 2] = v.z; Ts[r][c4 + 3] = v.w;
    __syncthreads();
    #pragma unroll
    for (int i = 0; i < 4; ++i)
        Wt[(long)(n0 + r) * Kd + k0 + c4 + i] = f2b(Ts[c4 + i][r]);
}

// ---------------------------------------------------------------------------
extern "C" void kernel_launch(void* const* d_in, const int* in_sizes, int n_in,
                              void* d_out, int out_size, void* d_ws, size_t ws_size,
                              hipStream_t stream) {
    (void)in_sizes; (void)n_in; (void)out_size;
    const float* x     = (const float*)d_in[0];
    const float* Wkqv  = (const float*)d_in[1];
    const float* Wproj = (const float*)d_in[2];
    const float* g1    = (const float*)d_in[3];
    const float* b1    = (const float*)d_in[4];
    const float* W1    = (const float*)d_in[5];
    const float* bff1  = (const float*)d_in[6];
    const float* W2    = (const float*)d_in[7];
    const float* bff2  = (const float*)d_in[8];
    const float* g2    = (const float*)d_in[9];
    const float* b2    = (const float*)d_in[10];
    float* out = (float*)d_out;
    char* ws = (char*)d_ws;

    // layout (MB offsets), 90 MB base envelope (proven in prior rounds):
    //  0.. 8 Qb -> x1b     8..40 Kb/Vb/resb -> hb
    // 40..48 VT (dead after attn) -> mp0/fp0   48..56 mp1/fp1
    // 48..64 Opb (attn partials, dead after combine; mp1 overwrites later)
    // 64..64.5 lpb   72..74 Wpt  74..82 W1t  82..90 W2t  90 Wqt
    // big path (ws >= 108 MB): fp2 at 91, fp3 at 99
    const size_t MB = 1u << 20;
    unsigned short* Qb   = (unsigned short*)(ws + 0 * MB);
    unsigned short* Kb   = (unsigned short*)(ws + 8 * MB);
    unsigned short* Vb   = (unsigned short*)(ws + 16 * MB);
    unsigned short* resb = (unsigned short*)(ws + 24 * MB);
    unsigned short* hb   = (unsigned short*)(ws + 8 * MB);    // 32 MB (8..40)
    unsigned short* VTb  = (unsigned short*)(ws + 40 * MB);   // 8 MB
    unsigned short* mp0  = (unsigned short*)(ws + 40 * MB);
    unsigned short* mp1  = (unsigned short*)(ws + 48 * MB);
    unsigned short* Opb  = (unsigned short*)(ws + 48 * MB);   // 16 MB (48..64)
    float*          lpb  = (float*)         (ws + 64 * MB);   // 512 KB
    unsigned short* x1b  = Qb;
    unsigned short* Wpt  = (unsigned short*)(ws + 72 * MB);
    unsigned short* W1t  = (unsigned short*)(ws + 74 * MB);
    unsigned short* W2t  = (unsigned short*)(ws + 82 * MB);
    unsigned short* Wqt  = (unsigned short*)(ws + 90 * MB);
    unsigned short* fp2  = (unsigned short*)(ws + 91 * MB);
    unsigned short* fp3  = (unsigned short*)(ws + 99 * MB);
    const bool big = ws_size >= 108 * MB;   // constant per-process -> graph-safe

    // weight prep (single fused dispatch; every call - no persistent state)
    transp_all<<<dim3(9228), 256, 0, stream>>>(Wproj, W1, W2, Wkqv, Wpt, W1t, W2t, Wqt);

    // 1. kqv projection (MFMA, bf16 out, x-row order) + V transpose
    kqv_kernel<<<dim3(ROWS/128), 256, 0, stream>>>(x, Wqt, Kb, Qb, Vb);
    vt_kernel<<<dim3(T_/64, B_*H_), 256, 0, stream>>>(Vb, VTb);
    // 2. flash attention, 4-wave blocks, kv-split=2 -> 1024 blocks;
    //    partials combined exactly (no online max -> sums add)
    attn_kernel<<<dim3(512, 2), 256, 0, stream>>>(Qb, Kb, VTb, Opb, lpb);
    attn_combine<<<dim3(ROWS*16/256), 256, 0, stream>>>(Opb, lpb, resb);
    // 3. mha = res @ Wproj, split-K=2 (bf16 partials; summed in LN1)
    P4 mp; mp.p[0] = mp0; mp.p[1] = mp1; mp.p[2] = nullptr; mp.p[3] = nullptr;
    gemm_splitk<<<dim3(EMB/128, BT/128, 2), 256, 0, stream>>>(resb, Wpt, mp, BT, EMB, EMB, EMB/2);
    // 4. x1 = LN(x + mp0 + mp1)  (bf16 only)
    ln_kernel<2, 0><<<dim3(BT), 256, 0, stream>>>(x, mp, nullptr, g1, b1, nullptr, x1b);
    // 5. h = gelu(x1 @ W1 + bff1) (bf16 out)
    gemm_gelu<<<dim3(FF/128, BT/128), 256, 0, stream>>>(x1b, W1t, bff1, hb, BT, FF, EMB);
    // 6+7. ff = h @ W2 (split-K), then out = LN(x1b + sum(fp) + bff2)
    if (big) {
        P4 fp; fp.p[0] = mp0; fp.p[1] = mp1; fp.p[2] = fp2; fp.p[3] = fp3;
        gemm_splitk<<<dim3(EMB/128, BT/128, 4), 256, 0, stream>>>(hb, W2t, fp, BT, EMB, FF, FF/4);
        ln_kernel<4, 1><<<dim3(BT), 256, 0, stream>>>(x1b, fp, bff2, g2, b2, out, nullptr);
    } else {
        P4 fp; fp.p[0] = mp0; fp.p[1] = mp1; fp.p[2] = nullptr; fp.p[3] = nullptr;
        gemm_splitk<<<dim3(EMB/128, BT/128, 2), 256, 0, stream>>>(hb, W2t, fp, BT, EMB, FF, FF/2);
        ln_kernel<2, 1><<<dim3(BT), 256, 0, stream>>>(x1b, fp, bff2, g2, b2, out, nullptr);
    }
}

// Round 10
// 323.944 us; speedup vs baseline: 1.5129x; 1.0570x over previous
//
#include <hip/hip_runtime.h>
#include <hip/hip_bf16.h>
#include <math.h>

#define B_ 2
#define T_ 2048
#define H_ 16
#define S_ 64
#define EMB 1024
#define FF 4096
#define BT (B_*T_)        // 4096 rows
#define ROWS (B_*T_*H_)   // 65536

typedef __attribute__((ext_vector_type(8))) short s16x8;   // 8 bf16 (4 VGPRs)
typedef __attribute__((ext_vector_type(4))) float f32x4;   // MFMA C/D

struct P4 { unsigned short* p[4]; };   // partial-sum pointers (bf16)

__device__ __forceinline__ unsigned short f2b(float f) {
    return __builtin_bit_cast(unsigned short, __float2bfloat16(f));
}
__device__ __forceinline__ float b2f(short u) {
    return __builtin_bit_cast(float, ((unsigned int)(unsigned short)u) << 16);
}

// async global->LDS, 16B per lane (LDS dest = wave-uniform base + lane*16;
// GLOBAL address may be fully per-lane - only the LDS side is constrained)
__device__ __forceinline__ void gl_lds16(const void* g, void* l) {
    __builtin_amdgcn_global_load_lds(
        (const __attribute__((address_space(1))) void*)g,
        (__attribute__((address_space(3))) void*)l, 16, 0, 0);
}

__device__ __forceinline__ f32x4 mfma16(s16x8 a, s16x8 b, f32x4 c) {
    return __builtin_amdgcn_mfma_f32_16x16x32_bf16(a, b, c, 0, 0, 0);
}

// s_waitcnt simm16 (gfx9): vmcnt[3:0]|hi[15:14], expcnt[6:4], lgkmcnt[11:8]
#define WAIT_VM4 0x0F74   // vmcnt(4)
#define WAIT_VM2 0x0F72   // vmcnt(2)
#define WAIT_VM0 0x0F70   // vmcnt(0)

// R6 LDS bank-conflict swizzle (rule #21: linear gl_lds dest + inverse-
// permuted GLOBAL source + same-permuted read). Tiles are [row][64B]:
// read slot was (4*(row&1)+quad)&7 -> 8 lanes/slot (8-way conflict).
// chunk' = chunk ^ ((row>>1)&3) spreads 16 l15-lanes over all 8 slots
// (2/slot = free). Staged row = c*16 + (lane>>2) -> key = (lane>>3)&3.

// ---------------------------------------------------------------------------
// Kernel 1: kqv, MFMA version. x [ROWS][64] fp32, Wqt [192][64] bf16.
// Outputs K,Q,V bf16 in x-row order: [ (b*T+t)*H+h ][64].
// ---------------------------------------------------------------------------
__global__ __launch_bounds__(256) void kqv_kernel(const float* __restrict__ x,
        const unsigned short* __restrict__ Wqt, unsigned short* __restrict__ K,
        unsigned short* __restrict__ Q, unsigned short* __restrict__ V) {
    const int tid = threadIdx.x;
    const int w = tid >> 6, lane = tid & 63;
    const int l15 = lane & 15, quad = lane >> 4;
    const long r0 = (long)blockIdx.x * 128 + w * 32;

    s16x8 af[2][2];
    #pragma unroll
    for (int mt = 0; mt < 2; ++mt)
        #pragma unroll
        for (int ks = 0; ks < 2; ++ks) {
            const float* xp = x + (r0 + mt*16 + l15) * 64 + ks*32 + quad*8;
            const float4 v0 = *(const float4*)xp;
            const float4 v1 = *(const float4*)(xp + 4);
            s16x8 a;
            a[0] = (short)f2b(v0.x); a[1] = (short)f2b(v0.y);
            a[2] = (short)f2b(v0.z); a[3] = (short)f2b(v0.w);
            a[4] = (short)f2b(v1.x); a[5] = (short)f2b(v1.y);
            a[6] = (short)f2b(v1.z); a[7] = (short)f2b(v1.w);
            af[mt][ks] = a;
        }

    #pragma unroll
    for (int nt = 0; nt < 12; ++nt) {
        const s16x8 b0 = *(const s16x8*)&Wqt[(nt*16 + l15)*64 + quad*8];
        const s16x8 b1 = *(const s16x8*)&Wqt[(nt*16 + l15)*64 + 32 + quad*8];
        f32x4 acc[2] = {};
        #pragma unroll
        for (int mt = 0; mt < 2; ++mt) {
            acc[mt] = mfma16(af[mt][0], b0, acc[mt]);
            acc[mt] = mfma16(af[mt][1], b1, acc[mt]);
        }
        unsigned short* dst = (nt < 4) ? K : (nt < 8) ? Q : V;
        const int c0 = (nt & 3) * 16 + l15;
        #pragma unroll
        for (int mt = 0; mt < 2; ++mt)
            #pragma unroll
            for (int r = 0; r < 4; ++r)
                dst[(r0 + mt*16 + quad*4 + r) * 64 + c0] = f2b(acc[mt][r]);
    }
}

// ---------------------------------------------------------------------------
// Kernel 1b: V [ (b,t,h) ][d] -> VT [bh][d][t]  (64x64 tiles per (b,h))
// ---------------------------------------------------------------------------
__global__ __launch_bounds__(256) void vt_kernel(const unsigned short* __restrict__ V,
        unsigned short* __restrict__ VT) {
    __shared__ unsigned short Ts[64][72];
    const int tid = threadIdx.x;
    const int tt = blockIdx.x, bh = blockIdx.y;
    const int b = bh >> 4, h = bh & 15;
    const long vbase = ((long)b * (T_*H_) + h) * 64;   // + t*1024 + d
    #pragma unroll
    for (int i = 0; i < 2; ++i) {
        const int id = i * 256 + tid;          // 0..511
        const int tr = id >> 3, dc = (id & 7) * 8;
        const s16x8 v = *(const s16x8*)&V[vbase + (long)(tt*64 + tr)*1024 + dc];
        *(s16x8*)&Ts[tr][dc] = v;
    }
    __syncthreads();
    #pragma unroll
    for (int i = 0; i < 2; ++i) {
        const int id = i * 256 + tid;
        const int d = id >> 3, tc = (id & 7) * 8;
        s16x8 o;
        #pragma unroll
        for (int j = 0; j < 8; ++j) o[j] = (short)Ts[tc + j][d];
        *(s16x8*)&VT[((long)bh*64 + d)*2048 + tt*64 + tc] = o;
    }
}

// ---------------------------------------------------------------------------
// Kernel 2 (R6): flash attention, 4-wave blocks, kv-split=2, swizzled LDS.
// K/V LDS reads conflict-free via source-side swizzle + XOR'd read chunk.
// Ps pad 40 for 16B-aligned conflict-free P reloads.
// ---------------------------------------------------------------------------
__global__ __launch_bounds__(256) void attn_kernel(const unsigned short* __restrict__ Q,
        const unsigned short* __restrict__ K, const unsigned short* __restrict__ VT,
        unsigned short* __restrict__ Op, float* __restrict__ lp) {
    __shared__ __align__(16) unsigned short Kbuf[2][2][32*32];  // [buf][dhalf][j][d32]
    __shared__ __align__(16) unsigned short Vbuf[2][64*32];     // [buf][d][t32]
    __shared__ __align__(16) unsigned short Ps[4][32*40];       // per-wave [q][j], pad 40
    const int tid = threadIdx.x;
    const int wid = tid >> 6, lane = tid & 63;
    const int l15 = lane & 15, quad = lane >> 4;
    const int bid = blockIdx.x;
    const int s = blockIdx.y;                 // kv-split index (0,1)
    const int qg = bid & 15, bh = bid >> 4;   // 16 q-groups consecutive -> L2 locality per bh
    const long base = ((long)(bh >> 4) * (T_*H_) + (bh & 15)) * 64;  // x-row order
    const unsigned short* Qp = Q + base;
    const unsigned short* Kp = K + base;
    const unsigned short* Vp = VT + (long)bh * 64 * 2048;   // [d][t]
    const int q0 = qg * 128 + wid * 32;
    const int kt0 = s * 32;                   // 32 key-tiles per split
    unsigned short* ps = &Ps[wid][0];
    const int rk = (l15 >> 1) & 3;            // read-side swizzle key
    const int sc8 = ((lane & 3) ^ ((lane >> 3) & 3)) * 8;   // staged source chunk

    // Q fragments (B-operand layout), pre-scaled by 1/8 (exact in bf16)
    s16x8 qf[2][2];
    #pragma unroll
    for (int qq = 0; qq < 2; ++qq)
        #pragma unroll
        for (int ks = 0; ks < 2; ++ks) {
            const s16x8 raw = *(const s16x8*)&Qp[(long)(q0 + qq*16 + l15)*1024 + ks*32 + quad*8];
            s16x8 q;
            #pragma unroll
            for (int j = 0; j < 8; ++j) q[j] = (short)f2b(b2f(raw[j]) * 0.125f);
            qf[qq][ks] = q;
        }

    s16x8 onef;
    #pragma unroll
    for (int j = 0; j < 8; ++j) onef[j] = (short)0x3F80;   // bf16 1.0

    f32x4 oacc[2][4] = {};
    f32x4 lacc[2] = {};

    const int j16 = lane >> 2;           // staging row within 16-row call

    // stage: 8 x 1KB gl_lds calls split across 4 waves (2 per wave).
    // Global source column carries the inverse swizzle (sc8).
    auto stage = [&](int bufi, int kt) {
        char* kl = (char*)&Kbuf[bufi][0][0];
        char* vl = (char*)&Vbuf[bufi][0];
        const unsigned short* kg = Kp + (long)(kt*32) * 1024;
        const unsigned short* vg = Vp + kt*32 + sc8;
        switch (wid) {
        case 0:
            gl_lds16(kg + (long)j16*1024 + sc8,           kl +    0 + lane*16);
            gl_lds16(kg + (long)(j16+16)*1024 + sc8,      kl + 1024 + lane*16);
            break;
        case 1:
            gl_lds16(kg + (long)j16*1024 + 32 + sc8,      kl + 2048 + lane*16);
            gl_lds16(kg + (long)(j16+16)*1024 + 32 + sc8, kl + 3072 + lane*16);
            break;
        case 2:
            gl_lds16(vg + (long)(j16     )*2048, vl +    0 + lane*16);
            gl_lds16(vg + (long)(j16 + 16)*2048, vl + 1024 + lane*16);
            break;
        default:
            gl_lds16(vg + (long)(j16 + 32)*2048, vl + 2048 + lane*16);
            gl_lds16(vg + (long)(j16 + 48)*2048, vl + 3072 + lane*16);
            break;
        }
    };

    auto compute = [&](int bufi) {
        // S^T = K Q^T : A=K from LDS (swizzled read), B=Q regs
        f32x4 sT[2][2] = {};
        #pragma unroll
        for (int ks = 0; ks < 2; ++ks)
            #pragma unroll
            for (int jt = 0; jt < 2; ++jt) {
                const s16x8 kf = *(const s16x8*)&Kbuf[bufi][ks][(jt*16 + l15)*32 + (quad ^ rk)*8];
                sT[jt][0] = mfma16(kf, qf[0][ks], sT[jt][0]);
                sT[jt][1] = mfma16(kf, qf[1][ks], sT[jt][1]);
            }
        // P = exp(S): pack 4 j-consecutive values -> b64 store to ps[q][j]
        #pragma unroll
        for (int jt = 0; jt < 2; ++jt)
            #pragma unroll
            for (int qq = 0; qq < 2; ++qq) {
                uint2 pk;
                pk.x = (unsigned int)f2b(__expf(sT[jt][qq][0]))
                     | ((unsigned int)f2b(__expf(sT[jt][qq][1])) << 16);
                pk.y = (unsigned int)f2b(__expf(sT[jt][qq][2]))
                     | ((unsigned int)f2b(__expf(sT[jt][qq][3])) << 16);
                *(uint2*)&ps[(qq*16 + l15)*40 + jt*16 + quad*4] = pk;
            }
        // O += P V ; l += P 1   (wave-private LDS, DS in-order per wave)
        s16x8 pf[2];
        #pragma unroll
        for (int qq = 0; qq < 2; ++qq) {
            pf[qq] = *(const s16x8*)&ps[(qq*16 + l15)*40 + quad*8];
            lacc[qq] = mfma16(pf[qq], onef, lacc[qq]);
        }
        #pragma unroll
        for (int nt = 0; nt < 4; ++nt) {
            const s16x8 vf = *(const s16x8*)&Vbuf[bufi][(nt*16 + l15)*32 + (quad ^ rk)*8];
            oacc[0][nt] = mfma16(pf[0], vf, oacc[0][nt]);
            oacc[1][nt] = mfma16(pf[1], vf, oacc[1][nt]);
        }
    };

    stage(0, kt0);
    for (int kt = 0; kt < 31; ++kt) {
        stage((kt + 1) & 1, kt0 + kt + 1);           // prefetch next tile
        __builtin_amdgcn_s_waitcnt(WAIT_VM2);        // own 2 loads of tile kt landed
        __builtin_amdgcn_s_barrier();                // all waves' tile-kt loads landed
        __builtin_amdgcn_sched_barrier(0);
        compute(kt & 1);
        __builtin_amdgcn_s_barrier();                // buf kt&1 readers done before t+2 overwrite
        __builtin_amdgcn_sched_barrier(0);
    }
    __builtin_amdgcn_s_waitcnt(WAIT_VM0);
    __builtin_amdgcn_s_barrier();
    __builtin_amdgcn_sched_barrier(0);
    compute(1);   // kt = 31 (31 & 1 = 1)

    // epilogue: unnormalized O partial (bf16) + l partial (fp32).
    // Op layout [s][bh][t][d], lp layout [s][bh][t]; combined later.
    unsigned short* op = Op + ((long)s * 32 + bh) * 2048 * 64;
    float* lrow = lp + ((long)s * 32 + bh) * 2048;
    #pragma unroll
    for (int qq = 0; qq < 2; ++qq)
        #pragma unroll
        for (int r = 0; r < 4; ++r) {
            const int t = q0 + qq*16 + quad*4 + r;
            if (l15 == 0) lrow[t] = lacc[qq][r];
            #pragma unroll
            for (int nt = 0; nt < 4; ++nt)
                op[(long)t*64 + nt*16 + l15] = f2b(oacc[qq][nt][r]);
        }
}

// ---------------------------------------------------------------------------
// Kernel 2b (R3): combine kv-split partials: res = (O0+O1)/(l0+l1),
// written in x-row order [(b*T+t)*EMB + h*64 + d] for the Wproj GEMM.
// ---------------------------------------------------------------------------
__global__ __launch_bounds__(256) void attn_combine(const unsigned short* __restrict__ Op,
        const float* __restrict__ lp, unsigned short* __restrict__ res) {
    const int gid = blockIdx.x * 256 + threadIdx.x;
    const int row = gid >> 4;              // bh*2048 + t
    const int c4 = (gid & 15) * 4;
    const int bh = row >> 11, t = row & 2047;
    const int b = bh >> 4, h = bh & 15;
    const float inv = 1.f / (lp[row] + lp[ROWS + row]);
    const ushort4 u0 = *(const ushort4*)&Op[(long)row * 64 + c4];
    const ushort4 u1 = *(const ushort4*)&Op[((long)ROWS + row) * 64 + c4];
    unsigned short* r = res + ((long)(b*T_ + t)) * EMB + h*64 + c4;
    r[0] = f2b((b2f((short)u0.x) + b2f((short)u1.x)) * inv);
    r[1] = f2b((b2f((short)u0.y) + b2f((short)u1.y)) * inv);
    r[2] = f2b((b2f((short)u0.z) + b2f((short)u1.z)) * inv);
    r[3] = f2b((b2f((short)u0.w) + b2f((short)u1.w)) * inv);
}

// ---------------------------------------------------------------------------
// Kernel 3a (R6/R9): bf16 MFMA GEMM, two-buffer counted-vmcnt protocol +
// LDS bank-conflict swizzle. Best-measured GEMM configuration (R6: 334 us
// total). Per tile t: stage(t+1) -> vmcnt(4)[own t loads; t+1's in
// flight] -> barrier -> ds_read+MFMA -> barrier.
// ---------------------------------------------------------------------------
__global__ __launch_bounds__(256) void gemm_gelu(const unsigned short* __restrict__ A,
        const unsigned short* __restrict__ Bt, const float* __restrict__ bias,
        unsigned short* __restrict__ C, int M, int N, int Kd) {
    __shared__ __align__(16) unsigned short As[2][128 * 32];
    __shared__ __align__(16) unsigned short Bs[2][128 * 32];
    const int tid = threadIdx.x;
    const int w = tid >> 6, lane = tid & 63;
    const int l15 = lane & 15, quad = lane >> 4;
    const int wm = w >> 1, wn = w & 1;
    const int bn = blockIdx.x, bm = blockIdx.y;
    const int sr = lane >> 2;
    const int sskq = (lane & 3) ^ ((lane >> 3) & 3);   // swizzled source chunk
    const int rk = (l15 >> 1) & 3;                     // read-side key
    f32x4 acc[4][4] = {};
    const long arow = (long)(bm*128 + w*32 + sr);
    const long brow = (long)(bn*128 + w*32 + sr);

    auto stage = [&](int bi, int kt) {
        char* as = (char*)&As[bi][0];
        char* bs = (char*)&Bs[bi][0];
        gl_lds16(A  + (arow     )*Kd + kt + sskq*8, as + (w*32     )*64 + lane*16);
        gl_lds16(A  + (arow + 16)*Kd + kt + sskq*8, as + (w*32 + 16)*64 + lane*16);
        gl_lds16(Bt + (brow     )*Kd + kt + sskq*8, bs + (w*32     )*64 + lane*16);
        gl_lds16(Bt + (brow + 16)*Kd + kt + sskq*8, bs + (w*32 + 16)*64 + lane*16);
    };

    const int NT = Kd >> 5;
    stage(0, 0);
    int bi = 0;
    for (int t = 0; t < NT; ++t) {
        if (t + 1 < NT) {
            stage(bi ^ 1, (t + 1) * 32);             // prefetch next tile
            __builtin_amdgcn_s_waitcnt(WAIT_VM4);    // own tile-t 4 loads landed
        } else {
            __builtin_amdgcn_s_waitcnt(WAIT_VM0);
        }
        __builtin_amdgcn_s_barrier();                // all waves' tile-t loads landed
        __builtin_amdgcn_sched_barrier(0);
        s16x8 af[4], bf[4];
        #pragma unroll
        for (int mt = 0; mt < 4; ++mt)
            af[mt] = *(const s16x8*)&As[bi][(wm*64 + mt*16 + l15)*32 + (quad ^ rk)*8];
        #pragma unroll
        for (int nt = 0; nt < 4; ++nt)
            bf[nt] = *(const s16x8*)&Bs[bi][(wn*64 + nt*16 + l15)*32 + (quad ^ rk)*8];
        #pragma unroll
        for (int mt = 0; mt < 4; ++mt)
            #pragma unroll
            for (int nt = 0; nt < 4; ++nt)
                acc[mt][nt] = mfma16(af[mt], bf[nt], acc[mt][nt]);
        __builtin_amdgcn_s_barrier();                // readers done before overwrite
        __builtin_amdgcn_sched_barrier(0);
        bi ^= 1;
    }

    #pragma unroll
    for (int mt = 0; mt < 4; ++mt) {
        const int row0 = bm*128 + wm*64 + mt*16 + quad*4;
        #pragma unroll
        for (int nt = 0; nt < 4; ++nt) {
            const int col = bn*128 + wn*64 + nt*16 + l15;
            const float bv = bias[col];
            #pragma unroll
            for (int r = 0; r < 4; ++r) {
                float v = acc[mt][nt][r] + bv;
                v = 0.5f * v * (1.f + erff(v * 0.70710678118654752440f));
                C[(long)(row0 + r)*N + col] = f2b(v);
            }
        }
    }
}

// ---------------------------------------------------------------------------
// Kernel 3b (R6/R9): split-K GEMM, two-buffer counted-vmcnt + swizzle.
// R9: W2 uses split-2 (NT=64) - longer per-block K-runs amortize the
// prologue/ramp (m102 curve) and all 512 blocks are co-resident.
// ---------------------------------------------------------------------------
__global__ __launch_bounds__(256) void gemm_splitk(const unsigned short* __restrict__ A,
        const unsigned short* __restrict__ Bt, P4 parts, int M, int N, int Kd, int Ks) {
    __shared__ __align__(16) unsigned short As[2][128 * 32];
    __shared__ __align__(16) unsigned short Bs[2][128 * 32];
    const int tid = threadIdx.x;
    const int w = tid >> 6, lane = tid & 63;
    const int l15 = lane & 15, quad = lane >> 4;
    const int wm = w >> 1, wn = w & 1;
    const int bn = blockIdx.x, bm = blockIdx.y, s = blockIdx.z;
    const int sr = lane >> 2;
    const int sskq = (lane & 3) ^ ((lane >> 3) & 3);
    const int rk = (l15 >> 1) & 3;
    f32x4 acc[4][4] = {};
    const long arow = (long)(bm*128 + w*32 + sr);
    const long brow = (long)(bn*128 + w*32 + sr);
    const int k0 = s * Ks;

    auto stage = [&](int bi, int kt) {
        char* as = (char*)&As[bi][0];
        char* bs = (char*)&Bs[bi][0];
        gl_lds16(A  + (arow     )*Kd + kt + sskq*8, as + (w*32     )*64 + lane*16);
        gl_lds16(A  + (arow + 16)*Kd + kt + sskq*8, as + (w*32 + 16)*64 + lane*16);
        gl_lds16(Bt + (brow     )*Kd + kt + sskq*8, bs + (w*32     )*64 + lane*16);
        gl_lds16(Bt + (brow + 16)*Kd + kt + sskq*8, bs + (w*32 + 16)*64 + lane*16);
    };

    const int NT = Ks >> 5;
    stage(0, k0);
    int bi = 0;
    for (int t = 0; t < NT; ++t) {
        if (t + 1 < NT) {
            stage(bi ^ 1, k0 + (t + 1) * 32);
            __builtin_amdgcn_s_waitcnt(WAIT_VM4);
        } else {
            __builtin_amdgcn_s_waitcnt(WAIT_VM0);
        }
        __builtin_amdgcn_s_barrier();
        __builtin_amdgcn_sched_barrier(0);
        s16x8 af[4], bf[4];
        #pragma unroll
        for (int mt = 0; mt < 4; ++mt)
            af[mt] = *(const s16x8*)&As[bi][(wm*64 + mt*16 + l15)*32 + (quad ^ rk)*8];
        #pragma unroll
        for (int nt = 0; nt < 4; ++nt)
            bf[nt] = *(const s16x8*)&Bs[bi][(wn*64 + nt*16 + l15)*32 + (quad ^ rk)*8];
        #pragma unroll
        for (int mt = 0; mt < 4; ++mt)
            #pragma unroll
            for (int nt = 0; nt < 4; ++nt)
                acc[mt][nt] = mfma16(af[mt], bf[nt], acc[mt][nt]);
        __builtin_amdgcn_s_barrier();
        __builtin_amdgcn_sched_barrier(0);
        bi ^= 1;
    }

    unsigned short* Cp = parts.p[s];
    #pragma unroll
    for (int mt = 0; mt < 4; ++mt) {
        const int row0 = bm*128 + wm*64 + mt*16 + quad*4;
        #pragma unroll
        for (int nt = 0; nt < 4; ++nt) {
            const int col = bn*128 + wn*64 + nt*16 + l15;
            #pragma unroll
            for (int r = 0; r < 4; ++r)
                Cp[(long)(row0 + r)*N + col] = f2b(acc[mt][nt][r]);
        }
    }
}

// ---------------------------------------------------------------------------
// Kernel 4: out = LayerNorm(xa + sum(partials) [+ addb]) * g + b
// XBF: xa is bf16 (residual chain kept in bf16). Outputs optional.
// ---------------------------------------------------------------------------
template <int P, int XBF>
__global__ __launch_bounds__(256) void ln_kernel(const void* __restrict__ xa,
        P4 parts, const float* __restrict__ addb, const float* __restrict__ g,
        const float* __restrict__ bia, float* __restrict__ out,
        unsigned short* __restrict__ outb) {
    const int row = blockIdx.x;
    const int tid = threadIdx.x;
    float4 v;
    if (XBF) {
        const ushort4 u = ((const ushort4*)xa)[(long)row * (EMB/4) + tid];
        v.x = b2f((short)u.x); v.y = b2f((short)u.y);
        v.z = b2f((short)u.z); v.w = b2f((short)u.w);
    } else {
        v = ((const float4*)xa)[(long)row * (EMB/4) + tid];
    }
    #pragma unroll
    for (int p = 0; p < P; ++p) {
        const ushort4 u = ((const ushort4*)(parts.p[p] + (long)row * EMB))[tid];
        v.x += b2f((short)u.x); v.y += b2f((short)u.y);
        v.z += b2f((short)u.z); v.w += b2f((short)u.w);
    }
    if (addb) {
        const float4 ab = ((const float4*)addb)[tid];
        v.x += ab.x; v.y += ab.y; v.z += ab.z; v.w += ab.w;
    }
    float s = v.x + v.y + v.z + v.w;
    float ss = v.x * v.x + v.y * v.y + v.z * v.z + v.w * v.w;
    #pragma unroll
    for (int off = 32; off > 0; off >>= 1) {
        s += __shfl_down(s, off, 64);
        ss += __shfl_down(ss, off, 64);
    }
    __shared__ float ls[4], lss[4];
    __shared__ float mean_s, rstd_s;
    const int wid = tid >> 6, lane = tid & 63;
    if (lane == 0) { ls[wid] = s; lss[wid] = ss; }
    __syncthreads();
    if (tid == 0) {
        const float S0 = ls[0] + ls[1] + ls[2] + ls[3];
        const float S2 = lss[0] + lss[1] + lss[2] + lss[3];
        const float mean = S0 * (1.f / EMB);
        const float var = S2 * (1.f / EMB) - mean * mean;
        mean_s = mean;
        rstd_s = rsqrtf(var + 1e-5f);
    }
    __syncthreads();
    const float mean = mean_s, rstd = rstd_s;
    const float4 gg = ((const float4*)g)[tid];
    const float4 bb = ((const float4*)bia)[tid];
    float4 o;
    o.x = (v.x - mean) * rstd * gg.x + bb.x;
    o.y = (v.y - mean) * rstd * gg.y + bb.y;
    o.z = (v.z - mean) * rstd * gg.z + bb.z;
    o.w = (v.w - mean) * rstd * gg.w + bb.w;
    if (out) ((float4*)(out + (long)row * EMB))[tid] = o;
    if (outb) {
        unsigned short* ob = outb + (long)row * EMB + tid * 4;
        ob[0] = f2b(o.x); ob[1] = f2b(o.y); ob[2] = f2b(o.z); ob[3] = f2b(o.w);
    }
}

// ---------------------------------------------------------------------------
// Kernel 5: all weight transposes fused into one dispatch. 32x32 fp32->bf16.
// ---------------------------------------------------------------------------
__global__ __launch_bounds__(256) void transp_all(const float* __restrict__ Wp,
        const float* __restrict__ W1, const float* __restrict__ W2,
        const float* __restrict__ Wq, unsigned short* __restrict__ Wpt,
        unsigned short* __restrict__ W1t, unsigned short* __restrict__ W2t,
        unsigned short* __restrict__ Wqt) {
    int id = blockIdx.x;
    const float* W; unsigned short* Wt; int Kd, N, ntx;
    if (id < 1024)      {            W = Wp; Wt = Wpt; Kd = 1024; N = 1024; ntx = 32; }
    else if (id < 5120) { id -= 1024; W = W1; Wt = W1t; Kd = 1024; N = 4096; ntx = 128; }
    else if (id < 9216) { id -= 5120; W = W2; Wt = W2t; Kd = 4096; N = 1024; ntx = 32; }
    else                { id -= 9216; W = Wq; Wt = Wqt; Kd = 64;   N = 192;  ntx = 6;  }
    __shared__ float Ts[32][33];
    const int tid = threadIdx.x;
    const int n0 = (id % ntx) * 32, k0 = (id / ntx) * 32;
    const int r = tid >> 3, c4 = (tid & 7) * 4;
    const float4 v = *(const float4*)&W[(long)(k0 + r) * N + n0 + c4];
    Ts[r][c4] = v.x; Ts[r][c4 + 1] = v.y; Ts[r][c4 + 2] = v.z; Ts[r][c4 + 3] = v.w;
    __syncthreads();
    #pragma unroll
    for (int i = 0; i < 4; ++i)
        Wt[(long)(n0 + r) * Kd + k0 + c4 + i] = f2b(Ts[c4 + i][r]);
}

// ---------------------------------------------------------------------------
extern "C" void kernel_launch(void* const* d_in, const int* in_sizes, int n_in,
                              void* d_out, int out_size, void* d_ws, size_t ws_size,
                              hipStream_t stream) {
    (void)in_sizes; (void)n_in; (void)out_size; (void)ws_size;
    const float* x     = (const float*)d_in[0];
    const float* Wkqv  = (const float*)d_in[1];
    const float* Wproj = (const float*)d_in[2];
    const float* g1    = (const float*)d_in[3];
    const float* b1    = (const float*)d_in[4];
    const float* W1    = (const float*)d_in[5];
    const float* bff1  = (const float*)d_in[6];
    const float* W2    = (const float*)d_in[7];
    const float* bff2  = (const float*)d_in[8];
    const float* g2    = (const float*)d_in[9];
    const float* b2    = (const float*)d_in[10];
    float* out = (float*)d_out;
    char* ws = (char*)d_ws;

    // layout (MB offsets), 90 MB base envelope (proven in prior rounds):
    //  0.. 8 Qb -> x1b     8..40 Kb/Vb/resb -> hb
    // 40..48 VT (dead after attn) -> mp0/fp0   48..56 mp1/fp1
    // 48..64 Opb (attn partials, dead after combine; mp1 overwrites later)
    // 64..64.5 lpb   72..74 Wpt  74..82 W1t  82..90 W2t  90 Wqt
    const size_t MB = 1u << 20;
    unsigned short* Qb   = (unsigned short*)(ws + 0 * MB);
    unsigned short* Kb   = (unsigned short*)(ws + 8 * MB);
    unsigned short* Vb   = (unsigned short*)(ws + 16 * MB);
    unsigned short* resb = (unsigned short*)(ws + 24 * MB);
    unsigned short* hb   = (unsigned short*)(ws + 8 * MB);    // 32 MB (8..40)
    unsigned short* VTb  = (unsigned short*)(ws + 40 * MB);   // 8 MB
    unsigned short* mp0  = (unsigned short*)(ws + 40 * MB);
    unsigned short* mp1  = (unsigned short*)(ws + 48 * MB);
    unsigned short* Opb  = (unsigned short*)(ws + 48 * MB);   // 16 MB (48..64)
    float*          lpb  = (float*)         (ws + 64 * MB);   // 512 KB
    unsigned short* x1b  = Qb;
    unsigned short* Wpt  = (unsigned short*)(ws + 72 * MB);
    unsigned short* W1t  = (unsigned short*)(ws + 74 * MB);
    unsigned short* W2t  = (unsigned short*)(ws + 82 * MB);
    unsigned short* Wqt  = (unsigned short*)(ws + 90 * MB);

    // weight prep (single fused dispatch; every call - no persistent state)
    transp_all<<<dim3(9228), 256, 0, stream>>>(Wproj, W1, W2, Wkqv, Wpt, W1t, W2t, Wqt);

    // 1. kqv projection (MFMA, bf16 out, x-row order) + V transpose
    kqv_kernel<<<dim3(ROWS/128), 256, 0, stream>>>(x, Wqt, Kb, Qb, Vb);
    vt_kernel<<<dim3(T_/64, B_*H_), 256, 0, stream>>>(Vb, VTb);
    // 2. flash attention, 4-wave blocks, kv-split=2 -> 1024 blocks;
    //    partials combined exactly (no online max -> sums add)
    attn_kernel<<<dim3(512, 2), 256, 0, stream>>>(Qb, Kb, VTb, Opb, lpb);
    attn_combine<<<dim3(ROWS*16/256), 256, 0, stream>>>(Opb, lpb, resb);
    // 3. mha = res @ Wproj, split-K=2 (bf16 partials; summed in LN1)
    P4 mp; mp.p[0] = mp0; mp.p[1] = mp1; mp.p[2] = nullptr; mp.p[3] = nullptr;
    gemm_splitk<<<dim3(EMB/128, BT/128, 2), 256, 0, stream>>>(resb, Wpt, mp, BT, EMB, EMB, EMB/2);
    // 4. x1 = LN(x + mp0 + mp1)  (bf16 only)
    ln_kernel<2, 0><<<dim3(BT), 256, 0, stream>>>(x, mp, nullptr, g1, b1, nullptr, x1b);
    // 5. h = gelu(x1 @ W1 + bff1) (bf16 out)
    gemm_gelu<<<dim3(FF/128, BT/128), 256, 0, stream>>>(x1b, W1t, bff1, hb, BT, FF, EMB);
    // 6+7. ff = h @ W2 split-K=2 (NT=64 per block: long K-runs amortize
    //      ramp per m102; 512 blocks all co-resident), then final LN.
    P4 fp; fp.p[0] = mp0; fp.p[1] = mp1; fp.p[2] = nullptr; fp.p[3] = nullptr;
    gemm_splitk<<<dim3(EMB/128, BT/128, 2), 256, 0, stream>>>(hb, W2t, fp, BT, EMB, FF, FF/2);
    ln_kernel<2, 1><<<dim3(BT), 256, 0, stream>>>(x1b, fp, bff2, g2, b2, out, nullptr);
}

// Round 11
// 311.730 us; speedup vs baseline: 1.5722x; 1.0392x over previous
//
#include <hip/hip_runtime.h>
#include <hip/hip_bf16.h>
#include <math.h>

#define B_ 2
#define T_ 2048
#define H_ 16
#define S_ 64
#define EMB 1024
#define FF 4096
#define BT (B_*T_)        // 4096 rows
#define ROWS (B_*T_*H_)   // 65536

typedef __attribute__((ext_vector_type(8))) short s16x8;   // 8 bf16 (4 VGPRs)
typedef __attribute__((ext_vector_type(4))) float f32x4;   // MFMA C/D

struct P4 { unsigned short* p[4]; };   // partial-sum pointers (bf16)

__device__ __forceinline__ unsigned short f2b(float f) {
    return __builtin_bit_cast(unsigned short, __float2bfloat16(f));
}
__device__ __forceinline__ float b2f(short u) {
    return __builtin_bit_cast(float, ((unsigned int)(unsigned short)u) << 16);
}

// async global->LDS, 16B per lane (LDS dest = wave-uniform base + lane*16;
// GLOBAL address may be fully per-lane - only the LDS side is constrained)
__device__ __forceinline__ void gl_lds16(const void* g, void* l) {
    __builtin_amdgcn_global_load_lds(
        (const __attribute__((address_space(1))) void*)g,
        (__attribute__((address_space(3))) void*)l, 16, 0, 0);
}

__device__ __forceinline__ f32x4 mfma16(s16x8 a, s16x8 b, f32x4 c) {
    return __builtin_amdgcn_mfma_f32_16x16x32_bf16(a, b, c, 0, 0, 0);
}

// s_waitcnt simm16 (gfx9): vmcnt[3:0]|hi[15:14], expcnt[6:4], lgkmcnt[11:8]
#define WAIT_VM8 0x0F78   // vmcnt(8)
#define WAIT_VM4 0x0F74   // vmcnt(4)
#define WAIT_VM2 0x0F72   // vmcnt(2)
#define WAIT_VM0 0x0F70   // vmcnt(0)

// R10 GEMM swizzle (BK=64, [128][128B] rows -> slot = chunk, so key is
// 3 bits of row): staged source chunk = (lane&7)^(lane>>3) (staged row
// = base + lane>>3, row&7 == lane>>3); read chunk = (ks*4+quad)^(l15&7).
// Per-8-lane phase all 8 slots hit once (R6-verified pattern, 0 conflicts).
// Attn keeps R6's 2-bit swizzle (64B rows).

// ---------------------------------------------------------------------------
// Kernel 1: kqv, MFMA version. x [ROWS][64] fp32, Wqt [192][64] bf16.
// Outputs K,Q,V bf16 in x-row order: [ (b*T+t)*H+h ][64].
// ---------------------------------------------------------------------------
__global__ __launch_bounds__(256) void kqv_kernel(const float* __restrict__ x,
        const unsigned short* __restrict__ Wqt, unsigned short* __restrict__ K,
        unsigned short* __restrict__ Q, unsigned short* __restrict__ V) {
    const int tid = threadIdx.x;
    const int w = tid >> 6, lane = tid & 63;
    const int l15 = lane & 15, quad = lane >> 4;
    const long r0 = (long)blockIdx.x * 128 + w * 32;

    s16x8 af[2][2];
    #pragma unroll
    for (int mt = 0; mt < 2; ++mt)
        #pragma unroll
        for (int ks = 0; ks < 2; ++ks) {
            const float* xp = x + (r0 + mt*16 + l15) * 64 + ks*32 + quad*8;
            const float4 v0 = *(const float4*)xp;
            const float4 v1 = *(const float4*)(xp + 4);
            s16x8 a;
            a[0] = (short)f2b(v0.x); a[1] = (short)f2b(v0.y);
            a[2] = (short)f2b(v0.z); a[3] = (short)f2b(v0.w);
            a[4] = (short)f2b(v1.x); a[5] = (short)f2b(v1.y);
            a[6] = (short)f2b(v1.z); a[7] = (short)f2b(v1.w);
            af[mt][ks] = a;
        }

    #pragma unroll
    for (int nt = 0; nt < 12; ++nt) {
        const s16x8 b0 = *(const s16x8*)&Wqt[(nt*16 + l15)*64 + quad*8];
        const s16x8 b1 = *(const s16x8*)&Wqt[(nt*16 + l15)*64 + 32 + quad*8];
        f32x4 acc[2] = {};
        #pragma unroll
        for (int mt = 0; mt < 2; ++mt) {
            acc[mt] = mfma16(af[mt][0], b0, acc[mt]);
            acc[mt] = mfma16(af[mt][1], b1, acc[mt]);
        }
        unsigned short* dst = (nt < 4) ? K : (nt < 8) ? Q : V;
        const int c0 = (nt & 3) * 16 + l15;
        #pragma unroll
        for (int mt = 0; mt < 2; ++mt)
            #pragma unroll
            for (int r = 0; r < 4; ++r)
                dst[(r0 + mt*16 + quad*4 + r) * 64 + c0] = f2b(acc[mt][r]);
    }
}

// ---------------------------------------------------------------------------
// Kernel 1b: V [ (b,t,h) ][d] -> VT [bh][d][t]  (64x64 tiles per (b,h))
// ---------------------------------------------------------------------------
__global__ __launch_bounds__(256) void vt_kernel(const unsigned short* __restrict__ V,
        unsigned short* __restrict__ VT) {
    __shared__ unsigned short Ts[64][72];
    const int tid = threadIdx.x;
    const int tt = blockIdx.x, bh = blockIdx.y;
    const int b = bh >> 4, h = bh & 15;
    const long vbase = ((long)b * (T_*H_) + h) * 64;   // + t*1024 + d
    #pragma unroll
    for (int i = 0; i < 2; ++i) {
        const int id = i * 256 + tid;          // 0..511
        const int tr = id >> 3, dc = (id & 7) * 8;
        const s16x8 v = *(const s16x8*)&V[vbase + (long)(tt*64 + tr)*1024 + dc];
        *(s16x8*)&Ts[tr][dc] = v;
    }
    __syncthreads();
    #pragma unroll
    for (int i = 0; i < 2; ++i) {
        const int id = i * 256 + tid;
        const int d = id >> 3, tc = (id & 7) * 8;
        s16x8 o;
        #pragma unroll
        for (int j = 0; j < 8; ++j) o[j] = (short)Ts[tc + j][d];
        *(s16x8*)&VT[((long)bh*64 + d)*2048 + tt*64 + tc] = o;
    }
}

// ---------------------------------------------------------------------------
// Kernel 2 (R6): flash attention, 4-wave blocks, kv-split=2, swizzled LDS.
// K/V LDS reads conflict-free via source-side swizzle + XOR'd read chunk.
// Ps pad 40 for 16B-aligned conflict-free P reloads.
// ---------------------------------------------------------------------------
__global__ __launch_bounds__(256) void attn_kernel(const unsigned short* __restrict__ Q,
        const unsigned short* __restrict__ K, const unsigned short* __restrict__ VT,
        unsigned short* __restrict__ Op, float* __restrict__ lp) {
    __shared__ __align__(16) unsigned short Kbuf[2][2][32*32];  // [buf][dhalf][j][d32]
    __shared__ __align__(16) unsigned short Vbuf[2][64*32];     // [buf][d][t32]
    __shared__ __align__(16) unsigned short Ps[4][32*40];       // per-wave [q][j], pad 40
    const int tid = threadIdx.x;
    const int wid = tid >> 6, lane = tid & 63;
    const int l15 = lane & 15, quad = lane >> 4;
    const int bid = blockIdx.x;
    const int s = blockIdx.y;                 // kv-split index (0,1)
    const int qg = bid & 15, bh = bid >> 4;   // 16 q-groups consecutive -> L2 locality per bh
    const long base = ((long)(bh >> 4) * (T_*H_) + (bh & 15)) * 64;  // x-row order
    const unsigned short* Qp = Q + base;
    const unsigned short* Kp = K + base;
    const unsigned short* Vp = VT + (long)bh * 64 * 2048;   // [d][t]
    const int q0 = qg * 128 + wid * 32;
    const int kt0 = s * 32;                   // 32 key-tiles per split
    unsigned short* ps = &Ps[wid][0];
    const int rk = (l15 >> 1) & 3;            // read-side swizzle key
    const int sc8 = ((lane & 3) ^ ((lane >> 3) & 3)) * 8;   // staged source chunk

    // Q fragments (B-operand layout), pre-scaled by 1/8 (exact in bf16)
    s16x8 qf[2][2];
    #pragma unroll
    for (int qq = 0; qq < 2; ++qq)
        #pragma unroll
        for (int ks = 0; ks < 2; ++ks) {
            const s16x8 raw = *(const s16x8*)&Qp[(long)(q0 + qq*16 + l15)*1024 + ks*32 + quad*8];
            s16x8 q;
            #pragma unroll
            for (int j = 0; j < 8; ++j) q[j] = (short)f2b(b2f(raw[j]) * 0.125f);
            qf[qq][ks] = q;
        }

    s16x8 onef;
    #pragma unroll
    for (int j = 0; j < 8; ++j) onef[j] = (short)0x3F80;   // bf16 1.0

    f32x4 oacc[2][4] = {};
    f32x4 lacc[2] = {};

    const int j16 = lane >> 2;           // staging row within 16-row call

    // stage: 8 x 1KB gl_lds calls split across 4 waves (2 per wave).
    // Global source column carries the inverse swizzle (sc8).
    auto stage = [&](int bufi, int kt) {
        char* kl = (char*)&Kbuf[bufi][0][0];
        char* vl = (char*)&Vbuf[bufi][0];
        const unsigned short* kg = Kp + (long)(kt*32) * 1024;
        const unsigned short* vg = Vp + kt*32 + sc8;
        switch (wid) {
        case 0:
            gl_lds16(kg + (long)j16*1024 + sc8,           kl +    0 + lane*16);
            gl_lds16(kg + (long)(j16+16)*1024 + sc8,      kl + 1024 + lane*16);
            break;
        case 1:
            gl_lds16(kg + (long)j16*1024 + 32 + sc8,      kl + 2048 + lane*16);
            gl_lds16(kg + (long)(j16+16)*1024 + 32 + sc8, kl + 3072 + lane*16);
            break;
        case 2:
            gl_lds16(vg + (long)(j16     )*2048, vl +    0 + lane*16);
            gl_lds16(vg + (long)(j16 + 16)*2048, vl + 1024 + lane*16);
            break;
        default:
            gl_lds16(vg + (long)(j16 + 32)*2048, vl + 2048 + lane*16);
            gl_lds16(vg + (long)(j16 + 48)*2048, vl + 3072 + lane*16);
            break;
        }
    };

    auto compute = [&](int bufi) {
        // S^T = K Q^T : A=K from LDS (swizzled read), B=Q regs
        f32x4 sT[2][2] = {};
        #pragma unroll
        for (int ks = 0; ks < 2; ++ks)
            #pragma unroll
            for (int jt = 0; jt < 2; ++jt) {
                const s16x8 kf = *(const s16x8*)&Kbuf[bufi][ks][(jt*16 + l15)*32 + (quad ^ rk)*8];
                sT[jt][0] = mfma16(kf, qf[0][ks], sT[jt][0]);
                sT[jt][1] = mfma16(kf, qf[1][ks], sT[jt][1]);
            }
        // P = exp(S): pack 4 j-consecutive values -> b64 store to ps[q][j]
        #pragma unroll
        for (int jt = 0; jt < 2; ++jt)
            #pragma unroll
            for (int qq = 0; qq < 2; ++qq) {
                uint2 pk;
                pk.x = (unsigned int)f2b(__expf(sT[jt][qq][0]))
                     | ((unsigned int)f2b(__expf(sT[jt][qq][1])) << 16);
                pk.y = (unsigned int)f2b(__expf(sT[jt][qq][2]))
                     | ((unsigned int)f2b(__expf(sT[jt][qq][3])) << 16);
                *(uint2*)&ps[(qq*16 + l15)*40 + jt*16 + quad*4] = pk;
            }
        // O += P V ; l += P 1   (wave-private LDS, DS in-order per wave)
        s16x8 pf[2];
        #pragma unroll
        for (int qq = 0; qq < 2; ++qq) {
            pf[qq] = *(const s16x8*)&ps[(qq*16 + l15)*40 + quad*8];
            lacc[qq] = mfma16(pf[qq], onef, lacc[qq]);
        }
        #pragma unroll
        for (int nt = 0; nt < 4; ++nt) {
            const s16x8 vf = *(const s16x8*)&Vbuf[bufi][(nt*16 + l15)*32 + (quad ^ rk)*8];
            oacc[0][nt] = mfma16(pf[0], vf, oacc[0][nt]);
            oacc[1][nt] = mfma16(pf[1], vf, oacc[1][nt]);
        }
    };

    stage(0, kt0);
    for (int kt = 0; kt < 31; ++kt) {
        stage((kt + 1) & 1, kt0 + kt + 1);           // prefetch next tile
        __builtin_amdgcn_s_waitcnt(WAIT_VM2);        // own 2 loads of tile kt landed
        __builtin_amdgcn_s_barrier();                // all waves' tile-kt loads landed
        __builtin_amdgcn_sched_barrier(0);
        compute(kt & 1);
        __builtin_amdgcn_s_barrier();                // buf kt&1 readers done before t+2 overwrite
        __builtin_amdgcn_sched_barrier(0);
    }
    __builtin_amdgcn_s_waitcnt(WAIT_VM0);
    __builtin_amdgcn_s_barrier();
    __builtin_amdgcn_sched_barrier(0);
    compute(1);   // kt = 31 (31 & 1 = 1)

    // epilogue: unnormalized O partial (bf16) + l partial (fp32).
    // Op layout [s][bh][t][d], lp layout [s][bh][t]; combined later.
    unsigned short* op = Op + ((long)s * 32 + bh) * 2048 * 64;
    float* lrow = lp + ((long)s * 32 + bh) * 2048;
    #pragma unroll
    for (int qq = 0; qq < 2; ++qq)
        #pragma unroll
        for (int r = 0; r < 4; ++r) {
            const int t = q0 + qq*16 + quad*4 + r;
            if (l15 == 0) lrow[t] = lacc[qq][r];
            #pragma unroll
            for (int nt = 0; nt < 4; ++nt)
                op[(long)t*64 + nt*16 + l15] = f2b(oacc[qq][nt][r]);
        }
}

// ---------------------------------------------------------------------------
// Kernel 2b (R3): combine kv-split partials: res = (O0+O1)/(l0+l1),
// written in x-row order [(b*T+t)*EMB + h*64 + d] for the Wproj GEMM.
// ---------------------------------------------------------------------------
__global__ __launch_bounds__(256) void attn_combine(const unsigned short* __restrict__ Op,
        const float* __restrict__ lp, unsigned short* __restrict__ res) {
    const int gid = blockIdx.x * 256 + threadIdx.x;
    const int row = gid >> 4;              // bh*2048 + t
    const int c4 = (gid & 15) * 4;
    const int bh = row >> 11, t = row & 2047;
    const int b = bh >> 4, h = bh & 15;
    const float inv = 1.f / (lp[row] + lp[ROWS + row]);
    const ushort4 u0 = *(const ushort4*)&Op[(long)row * 64 + c4];
    const ushort4 u1 = *(const ushort4*)&Op[((long)ROWS + row) * 64 + c4];
    unsigned short* r = res + ((long)(b*T_ + t)) * EMB + h*64 + c4;
    r[0] = f2b((b2f((short)u0.x) + b2f((short)u1.x)) * inv);
    r[1] = f2b((b2f((short)u0.y) + b2f((short)u1.y)) * inv);
    r[2] = f2b((b2f((short)u0.z) + b2f((short)u1.z)) * inv);
    r[3] = f2b((b2f((short)u0.w) + b2f((short)u1.w)) * inv);
}

// ---------------------------------------------------------------------------
// Kernel 3a (R10): bf16 MFMA GEMM, BK=64 two-buffer counted-vmcnt.
// 32 MFMA + 16 ds_read per barrier pair (2x R6's work per sync point,
// testing/exploiting the fixed-overhead theory from the R9 split-2 win).
// LDS 64KB total -> still 2 blocks/CU (VGPR-capped anyway; m132's BK=128
// cliff not triggered). 3-bit row-key swizzle for 128B rows.
// ---------------------------------------------------------------------------
__global__ __launch_bounds__(256) void gemm_gelu(const unsigned short* __restrict__ A,
        const unsigned short* __restrict__ Bt, const float* __restrict__ bias,
        unsigned short* __restrict__ C, int M, int N, int Kd) {
    __shared__ __align__(16) unsigned short As[2][128 * 64];
    __shared__ __align__(16) unsigned short Bs[2][128 * 64];
    const int tid = threadIdx.x;
    const int w = tid >> 6, lane = tid & 63;
    const int l15 = lane & 15, quad = lane >> 4;
    const int wm = w >> 1, wn = w & 1;
    const int bn = blockIdx.x, bm = blockIdx.y;
    const int sr8 = lane >> 3;                       // staged row within 8
    const int sk8 = ((lane & 7) ^ sr8) * 8;          // swizzled source k-chunk
    const int rk3 = l15 & 7;                         // read-side 3-bit key
    f32x4 acc[4][4] = {};

    auto stage = [&](int bi, int kt) {
        char* as = (char*)&As[bi][0];
        char* bs = (char*)&Bs[bi][0];
        #pragma unroll
        for (int c = 0; c < 4; ++c) {
            gl_lds16(A  + (long)(bm*128 + w*32 + c*8 + sr8)*Kd + kt + sk8,
                     as + (w*32 + c*8)*128 + lane*16);
            gl_lds16(Bt + (long)(bn*128 + w*32 + c*8 + sr8)*Kd + kt + sk8,
                     bs + (w*32 + c*8)*128 + lane*16);
        }
    };

    const int NT = Kd >> 6;
    stage(0, 0);
    int bi = 0;
    for (int t = 0; t < NT; ++t) {
        if (t + 1 < NT) {
            stage(bi ^ 1, (t + 1) * 64);             // prefetch next tile (8 loads)
            __builtin_amdgcn_s_waitcnt(WAIT_VM8);    // own tile-t 8 loads landed
        } else {
            __builtin_amdgcn_s_waitcnt(WAIT_VM0);
        }
        __builtin_amdgcn_s_barrier();                // all waves' tile-t loads landed
        __builtin_amdgcn_sched_barrier(0);
        #pragma unroll
        for (int ks = 0; ks < 2; ++ks) {
            s16x8 af[4], bf[4];
            #pragma unroll
            for (int mt = 0; mt < 4; ++mt)
                af[mt] = *(const s16x8*)&As[bi][(wm*64 + mt*16 + l15)*64 + (((ks<<2)|quad) ^ rk3)*8];
            #pragma unroll
            for (int nt = 0; nt < 4; ++nt)
                bf[nt] = *(const s16x8*)&Bs[bi][(wn*64 + nt*16 + l15)*64 + (((ks<<2)|quad) ^ rk3)*8];
            #pragma unroll
            for (int mt = 0; mt < 4; ++mt)
                #pragma unroll
                for (int nt = 0; nt < 4; ++nt)
                    acc[mt][nt] = mfma16(af[mt], bf[nt], acc[mt][nt]);
        }
        __builtin_amdgcn_s_barrier();                // readers done before overwrite
        __builtin_amdgcn_sched_barrier(0);
        bi ^= 1;
    }

    #pragma unroll
    for (int mt = 0; mt < 4; ++mt) {
        const int row0 = bm*128 + wm*64 + mt*16 + quad*4;
        #pragma unroll
        for (int nt = 0; nt < 4; ++nt) {
            const int col = bn*128 + wn*64 + nt*16 + l15;
            const float bv = bias[col];
            #pragma unroll
            for (int r = 0; r < 4; ++r) {
                float v = acc[mt][nt][r] + bv;
                v = 0.5f * v * (1.f + erff(v * 0.70710678118654752440f));
                C[(long)(row0 + r)*N + col] = f2b(v);
            }
        }
    }
}

// ---------------------------------------------------------------------------
// Kernel 3b (R10): split-K GEMM, same BK=64 structure as gemm_gelu.
// ---------------------------------------------------------------------------
__global__ __launch_bounds__(256) void gemm_splitk(const unsigned short* __restrict__ A,
        const unsigned short* __restrict__ Bt, P4 parts, int M, int N, int Kd, int Ks) {
    __shared__ __align__(16) unsigned short As[2][128 * 64];
    __shared__ __align__(16) unsigned short Bs[2][128 * 64];
    const int tid = threadIdx.x;
    const int w = tid >> 6, lane = tid & 63;
    const int l15 = lane & 15, quad = lane >> 4;
    const int wm = w >> 1, wn = w & 1;
    const int bn = blockIdx.x, bm = blockIdx.y, s = blockIdx.z;
    const int sr8 = lane >> 3;
    const int sk8 = ((lane & 7) ^ sr8) * 8;
    const int rk3 = l15 & 7;
    f32x4 acc[4][4] = {};
    const int k0 = s * Ks;

    auto stage = [&](int bi, int kt) {
        char* as = (char*)&As[bi][0];
        char* bs = (char*)&Bs[bi][0];
        #pragma unroll
        for (int c = 0; c < 4; ++c) {
            gl_lds16(A  + (long)(bm*128 + w*32 + c*8 + sr8)*Kd + kt + sk8,
                     as + (w*32 + c*8)*128 + lane*16);
            gl_lds16(Bt + (long)(bn*128 + w*32 + c*8 + sr8)*Kd + kt + sk8,
                     bs + (w*32 + c*8)*128 + lane*16);
        }
    };

    const int NT = Ks >> 6;
    stage(0, k0);
    int bi = 0;
    for (int t = 0; t < NT; ++t) {
        if (t + 1 < NT) {
            stage(bi ^ 1, k0 + (t + 1) * 64);
            __builtin_amdgcn_s_waitcnt(WAIT_VM8);
        } else {
            __builtin_amdgcn_s_waitcnt(WAIT_VM0);
        }
        __builtin_amdgcn_s_barrier();
        __builtin_amdgcn_sched_barrier(0);
        #pragma unroll
        for (int ks = 0; ks < 2; ++ks) {
            s16x8 af[4], bf[4];
            #pragma unroll
            for (int mt = 0; mt < 4; ++mt)
                af[mt] = *(const s16x8*)&As[bi][(wm*64 + mt*16 + l15)*64 + (((ks<<2)|quad) ^ rk3)*8];
            #pragma unroll
            for (int nt = 0; nt < 4; ++nt)
                bf[nt] = *(const s16x8*)&Bs[bi][(wn*64 + nt*16 + l15)*64 + (((ks<<2)|quad) ^ rk3)*8];
            #pragma unroll
            for (int mt = 0; mt < 4; ++mt)
                #pragma unroll
                for (int nt = 0; nt < 4; ++nt)
                    acc[mt][nt] = mfma16(af[mt], bf[nt], acc[mt][nt]);
        }
        __builtin_amdgcn_s_barrier();
        __builtin_amdgcn_sched_barrier(0);
        bi ^= 1;
    }

    unsigned short* Cp = parts.p[s];
    #pragma unroll
    for (int mt = 0; mt < 4; ++mt) {
        const int row0 = bm*128 + wm*64 + mt*16 + quad*4;
        #pragma unroll
        for (int nt = 0; nt < 4; ++nt) {
            const int col = bn*128 + wn*64 + nt*16 + l15;
            #pragma unroll
            for (int r = 0; r < 4; ++r)
                Cp[(long)(row0 + r)*N + col] = f2b(acc[mt][nt][r]);
        }
    }
}

// ---------------------------------------------------------------------------
// Kernel 4: out = LayerNorm(xa + sum(partials) [+ addb]) * g + b
// XBF: xa is bf16 (residual chain kept in bf16). Outputs optional.
// ---------------------------------------------------------------------------
template <int P, int XBF>
__global__ __launch_bounds__(256) void ln_kernel(const void* __restrict__ xa,
        P4 parts, const float* __restrict__ addb, const float* __restrict__ g,
        const float* __restrict__ bia, float* __restrict__ out,
        unsigned short* __restrict__ outb) {
    const int row = blockIdx.x;
    const int tid = threadIdx.x;
    float4 v;
    if (XBF) {
        const ushort4 u = ((const ushort4*)xa)[(long)row * (EMB/4) + tid];
        v.x = b2f((short)u.x); v.y = b2f((short)u.y);
        v.z = b2f((short)u.z); v.w = b2f((short)u.w);
    } else {
        v = ((const float4*)xa)[(long)row * (EMB/4) + tid];
    }
    #pragma unroll
    for (int p = 0; p < P; ++p) {
        const ushort4 u = ((const ushort4*)(parts.p[p] + (long)row * EMB))[tid];
        v.x += b2f((short)u.x); v.y += b2f((short)u.y);
        v.z += b2f((short)u.z); v.w += b2f((short)u.w);
    }
    if (addb) {
        const float4 ab = ((const float4*)addb)[tid];
        v.x += ab.x; v.y += ab.y; v.z += ab.z; v.w += ab.w;
    }
    float s = v.x + v.y + v.z + v.w;
    float ss = v.x * v.x + v.y * v.y + v.z * v.z + v.w * v.w;
    #pragma unroll
    for (int off = 32; off > 0; off >>= 1) {
        s += __shfl_down(s, off, 64);
        ss += __shfl_down(ss, off, 64);
    }
    __shared__ float ls[4], lss[4];
    __shared__ float mean_s, rstd_s;
    const int wid = tid >> 6, lane = tid & 63;
    if (lane == 0) { ls[wid] = s; lss[wid] = ss; }
    __syncthreads();
    if (tid == 0) {
        const float S0 = ls[0] + ls[1] + ls[2] + ls[3];
        const float S2 = lss[0] + lss[1] + lss[2] + lss[3];
        const float mean = S0 * (1.f / EMB);
        const float var = S2 * (1.f / EMB) - mean * mean;
        mean_s = mean;
        rstd_s = rsqrtf(var + 1e-5f);
    }
    __syncthreads();
    const float mean = mean_s, rstd = rstd_s;
    const float4 gg = ((const float4*)g)[tid];
    const float4 bb = ((const float4*)bia)[tid];
    float4 o;
    o.x = (v.x - mean) * rstd * gg.x + bb.x;
    o.y = (v.y - mean) * rstd * gg.y + bb.y;
    o.z = (v.z - mean) * rstd * gg.z + bb.z;
    o.w = (v.w - mean) * rstd * gg.w + bb.w;
    if (out) ((float4*)(out + (long)row * EMB))[tid] = o;
    if (outb) {
        unsigned short* ob = outb + (long)row * EMB + tid * 4;
        ob[0] = f2b(o.x); ob[1] = f2b(o.y); ob[2] = f2b(o.z); ob[3] = f2b(o.w);
    }
}

// ---------------------------------------------------------------------------
// Kernel 5: all weight transposes fused into one dispatch. 32x32 fp32->bf16.
// ---------------------------------------------------------------------------
__global__ __launch_bounds__(256) void transp_all(const float* __restrict__ Wp,
        const float* __restrict__ W1, const float* __restrict__ W2,
        const float* __restrict__ Wq, unsigned short* __restrict__ Wpt,
        unsigned short* __restrict__ W1t, unsigned short* __restrict__ W2t,
        unsigned short* __restrict__ Wqt) {
    int id = blockIdx.x;
    const float* W; unsigned short* Wt; int Kd, N, ntx;
    if (id < 1024)      {            W = Wp; Wt = Wpt; Kd = 1024; N = 1024; ntx = 32; }
    else if (id < 5120) { id -= 1024; W = W1; Wt = W1t; Kd = 1024; N = 4096; ntx = 128; }
    else if (id < 9216) { id -= 5120; W = W2; Wt = W2t; Kd = 4096; N = 1024; ntx = 32; }
    else                { id -= 9216; W = Wq; Wt = Wqt; Kd = 64;   N = 192;  ntx = 6;  }
    __shared__ float Ts[32][33];
    const int tid = threadIdx.x;
    const int n0 = (id % ntx) * 32, k0 = (id / ntx) * 32;
    const int r = tid >> 3, c4 = (tid & 7) * 4;
    const float4 v = *(const float4*)&W[(long)(k0 + r) * N + n0 + c4];
    Ts[r][c4] = v.x; Ts[r][c4 + 1] = v.y; Ts[r][c4 + 2] = v.z; Ts[r][c4 + 3] = v.w;
    __syncthreads();
    #pragma unroll
    for (int i = 0; i < 4; ++i)
        Wt[(long)(n0 + r) * Kd + k0 + c4 + i] = f2b(Ts[c4 + i][r]);
}

// ---------------------------------------------------------------------------
extern "C" void kernel_launch(void* const* d_in, const int* in_sizes, int n_in,
                              void* d_out, int out_size, void* d_ws, size_t ws_size,
                              hipStream_t stream) {
    (void)in_sizes; (void)n_in; (void)out_size; (void)ws_size;
    const float* x     = (const float*)d_in[0];
    const float* Wkqv  = (const float*)d_in[1];
    const float* Wproj = (const float*)d_in[2];
    const float* g1    = (const float*)d_in[3];
    const float* b1    = (const float*)d_in[4];
    const float* W1    = (const float*)d_in[5];
    const float* bff1  = (const float*)d_in[6];
    const float* W2    = (const float*)d_in[7];
    const float* bff2  = (const float*)d_in[8];
    const float* g2    = (const float*)d_in[9];
    const float* b2    = (const float*)d_in[10];
    float* out = (float*)d_out;
    char* ws = (char*)d_ws;

    // layout (MB offsets), 90 MB base envelope (proven in prior rounds):
    //  0.. 8 Qb -> x1b     8..40 Kb/Vb/resb -> hb
    // 40..48 VT (dead after attn) -> mp0/fp0   48..56 mp1/fp1
    // 48..64 Opb (attn partials, dead after combine; mp1 overwrites later)
    // 64..64.5 lpb   72..74 Wpt  74..82 W1t  82..90 W2t  90 Wqt
    const size_t MB = 1u << 20;
    unsigned short* Qb   = (unsigned short*)(ws + 0 * MB);
    unsigned short* Kb   = (unsigned short*)(ws + 8 * MB);
    unsigned short* Vb   = (unsigned short*)(ws + 16 * MB);
    unsigned short* resb = (unsigned short*)(ws + 24 * MB);
    unsigned short* hb   = (unsigned short*)(ws + 8 * MB);    // 32 MB (8..40)
    unsigned short* VTb  = (unsigned short*)(ws + 40 * MB);   // 8 MB
    unsigned short* mp0  = (unsigned short*)(ws + 40 * MB);
    unsigned short* mp1  = (unsigned short*)(ws + 48 * MB);
    unsigned short* Opb  = (unsigned short*)(ws + 48 * MB);   // 16 MB (48..64)
    float*          lpb  = (float*)         (ws + 64 * MB);   // 512 KB
    unsigned short* x1b  = Qb;
    unsigned short* Wpt  = (unsigned short*)(ws + 72 * MB);
    unsigned short* W1t  = (unsigned short*)(ws + 74 * MB);
    unsigned short* W2t  = (unsigned short*)(ws + 82 * MB);
    unsigned short* Wqt  = (unsigned short*)(ws + 90 * MB);

    // weight prep (single fused dispatch; every call - no persistent state)
    transp_all<<<dim3(9228), 256, 0, stream>>>(Wproj, W1, W2, Wkqv, Wpt, W1t, W2t, Wqt);

    // 1. kqv projection (MFMA, bf16 out, x-row order) + V transpose
    kqv_kernel<<<dim3(ROWS/128), 256, 0, stream>>>(x, Wqt, Kb, Qb, Vb);
    vt_kernel<<<dim3(T_/64, B_*H_), 256, 0, stream>>>(Vb, VTb);
    // 2. flash attention, 4-wave blocks, kv-split=2 -> 1024 blocks;
    //    partials combined exactly (no online max -> sums add)
    attn_kernel<<<dim3(512, 2), 256, 0, stream>>>(Qb, Kb, VTb, Opb, lpb);
    attn_combine<<<dim3(ROWS*16/256), 256, 0, stream>>>(Opb, lpb, resb);
    // 3. mha = res @ Wproj, split-K=2 (bf16 partials; summed in LN1)
    P4 mp; mp.p[0] = mp0; mp.p[1] = mp1; mp.p[2] = nullptr; mp.p[3] = nullptr;
    gemm_splitk<<<dim3(EMB/128, BT/128, 2), 256, 0, stream>>>(resb, Wpt, mp, BT, EMB, EMB, EMB/2);
    // 4. x1 = LN(x + mp0 + mp1)  (bf16 only)
    ln_kernel<2, 0><<<dim3(BT), 256, 0, stream>>>(x, mp, nullptr, g1, b1, nullptr, x1b);
    // 5. h = gelu(x1 @ W1 + bff1) (bf16 out)
    gemm_gelu<<<dim3(FF/128, BT/128), 256, 0, stream>>>(x1b, W1t, bff1, hb, BT, FF, EMB);
    // 6+7. ff = h @ W2 split-K=2 (NT=32 at BK=64), then final LN.
    P4 fp; fp.p[0] = mp0; fp.p[1] = mp1; fp.p[2] = nullptr; fp.p[3] = nullptr;
    gemm_splitk<<<dim3(EMB/128, BT/128, 2), 256, 0, stream>>>(hb, W2t, fp, BT, EMB, FF, FF/2);
    ln_kernel<2, 1><<<dim3(BT), 256, 0, stream>>>(x1b, fp, bff2, g2, b2, out, nullptr);
}

// Round 12
// 309.899 us; speedup vs baseline: 1.5815x; 1.0059x over previous
//
#include <hip/hip_runtime.h>
#include <hip/hip_bf16.h>
#include <math.h>

#define B_ 2
#define T_ 2048
#define H_ 16
#define S_ 64
#define EMB 1024
#define FF 4096
#define BT (B_*T_)        // 4096 rows
#define ROWS (B_*T_*H_)   // 65536

typedef __attribute__((ext_vector_type(8))) short s16x8;   // 8 bf16 (4 VGPRs)
typedef __attribute__((ext_vector_type(4))) float f32x4;   // MFMA C/D

struct P4 { unsigned short* p[4]; };   // partial-sum pointers (bf16)

__device__ __forceinline__ unsigned short f2b(float f) {
    return __builtin_bit_cast(unsigned short, __float2bfloat16(f));
}
__device__ __forceinline__ float b2f(short u) {
    return __builtin_bit_cast(float, ((unsigned int)(unsigned short)u) << 16);
}

// async global->LDS, 16B per lane (LDS dest = wave-uniform base + lane*16;
// GLOBAL address may be fully per-lane - only the LDS side is constrained)
__device__ __forceinline__ void gl_lds16(const void* g, void* l) {
    __builtin_amdgcn_global_load_lds(
        (const __attribute__((address_space(1))) void*)g,
        (__attribute__((address_space(3))) void*)l, 16, 0, 0);
}

__device__ __forceinline__ f32x4 mfma16(s16x8 a, s16x8 b, f32x4 c) {
    return __builtin_amdgcn_mfma_f32_16x16x32_bf16(a, b, c, 0, 0, 0);
}

// s_waitcnt simm16 (gfx9): vmcnt[3:0]|hi[15:14], expcnt[6:4], lgkmcnt[11:8]
#define WAIT_VM8 0x0F78   // vmcnt(8)
#define WAIT_VM4 0x0F74   // vmcnt(4)
#define WAIT_VM2 0x0F72   // vmcnt(2)
#define WAIT_VM0 0x0F70   // vmcnt(0)

// LDS swizzles (rule #21: linear gl_lds dest + inverse-permuted GLOBAL
// source + same-permuted read):
//  64B rows (K tiles):  2-bit key, read chunk = quad ^ ((l15>>1)&3),
//                       staged source chunk = (lane&3)^((lane>>3)&3).
//  128B rows (GEMM/V):  3-bit key, read chunk = c ^ (l15&7),
//                       staged source chunk = (lane&7)^(lane>>3).
// Both verified conflict-free (R6/R10: SQ_LDS_BANK_CONFLICT = 0).

// ---------------------------------------------------------------------------
// Kernel 1: kqv, MFMA version. x [ROWS][64] fp32, Wqt [192][64] bf16.
// Outputs K,Q,V bf16 in x-row order: [ (b*T+t)*H+h ][64].
// ---------------------------------------------------------------------------
__global__ __launch_bounds__(256) void kqv_kernel(const float* __restrict__ x,
        const unsigned short* __restrict__ Wqt, unsigned short* __restrict__ K,
        unsigned short* __restrict__ Q, unsigned short* __restrict__ V) {
    const int tid = threadIdx.x;
    const int w = tid >> 6, lane = tid & 63;
    const int l15 = lane & 15, quad = lane >> 4;
    const long r0 = (long)blockIdx.x * 128 + w * 32;

    s16x8 af[2][2];
    #pragma unroll
    for (int mt = 0; mt < 2; ++mt)
        #pragma unroll
        for (int ks = 0; ks < 2; ++ks) {
            const float* xp = x + (r0 + mt*16 + l15) * 64 + ks*32 + quad*8;
            const float4 v0 = *(const float4*)xp;
            const float4 v1 = *(const float4*)(xp + 4);
            s16x8 a;
            a[0] = (short)f2b(v0.x); a[1] = (short)f2b(v0.y);
            a[2] = (short)f2b(v0.z); a[3] = (short)f2b(v0.w);
            a[4] = (short)f2b(v1.x); a[5] = (short)f2b(v1.y);
            a[6] = (short)f2b(v1.z); a[7] = (short)f2b(v1.w);
            af[mt][ks] = a;
        }

    #pragma unroll
    for (int nt = 0; nt < 12; ++nt) {
        const s16x8 b0 = *(const s16x8*)&Wqt[(nt*16 + l15)*64 + quad*8];
        const s16x8 b1 = *(const s16x8*)&Wqt[(nt*16 + l15)*64 + 32 + quad*8];
        f32x4 acc[2] = {};
        #pragma unroll
        for (int mt = 0; mt < 2; ++mt) {
            acc[mt] = mfma16(af[mt][0], b0, acc[mt]);
            acc[mt] = mfma16(af[mt][1], b1, acc[mt]);
        }
        unsigned short* dst = (nt < 4) ? K : (nt < 8) ? Q : V;
        const int c0 = (nt & 3) * 16 + l15;
        #pragma unroll
        for (int mt = 0; mt < 2; ++mt)
            #pragma unroll
            for (int r = 0; r < 4; ++r)
                dst[(r0 + mt*16 + quad*4 + r) * 64 + c0] = f2b(acc[mt][r]);
    }
}

// ---------------------------------------------------------------------------
// Kernel 1b: V [ (b,t,h) ][d] -> VT [bh][d][t]  (64x64 tiles per (b,h))
// ---------------------------------------------------------------------------
__global__ __launch_bounds__(256) void vt_kernel(const unsigned short* __restrict__ V,
        unsigned short* __restrict__ VT) {
    __shared__ unsigned short Ts[64][72];
    const int tid = threadIdx.x;
    const int tt = blockIdx.x, bh = blockIdx.y;
    const int b = bh >> 4, h = bh & 15;
    const long vbase = ((long)b * (T_*H_) + h) * 64;   // + t*1024 + d
    #pragma unroll
    for (int i = 0; i < 2; ++i) {
        const int id = i * 256 + tid;          // 0..511
        const int tr = id >> 3, dc = (id & 7) * 8;
        const s16x8 v = *(const s16x8*)&V[vbase + (long)(tt*64 + tr)*1024 + dc];
        *(s16x8*)&Ts[tr][dc] = v;
    }
    __syncthreads();
    #pragma unroll
    for (int i = 0; i < 2; ++i) {
        const int id = i * 256 + tid;
        const int d = id >> 3, tc = (id & 7) * 8;
        s16x8 o;
        #pragma unroll
        for (int j = 0; j < 8; ++j) o[j] = (short)Ts[tc + j][d];
        *(s16x8*)&VT[((long)bh*64 + d)*2048 + tt*64 + tc] = o;
    }
}

// ---------------------------------------------------------------------------
// Kernel 2 (R11): flash attention, 4-wave blocks, kv-split=2, KVBLK=64.
// Same per-key MFMA/exp work as KVBLK=32 but HALF the barrier/stage/vmcnt
// events (16 iters/block instead of 32) - the R9/R10-confirmed fixed-
// overhead amortization applied to attention. K rows 64B (2-bit swizzle),
// V rows now 128B (3-bit swizzle). Ps stride 72 (conflict-free reads).
// ---------------------------------------------------------------------------
__global__ __launch_bounds__(256) void attn_kernel(const unsigned short* __restrict__ Q,
        const unsigned short* __restrict__ K, const unsigned short* __restrict__ VT,
        unsigned short* __restrict__ Op, float* __restrict__ lp) {
    __shared__ __align__(16) unsigned short Kbuf[2][2][64*32];  // [buf][dhalf][j64][d32]
    __shared__ __align__(16) unsigned short Vbuf[2][64*64];     // [buf][d][t64]
    __shared__ __align__(16) unsigned short Ps[4][32*72];       // per-wave [q][j64], pad 72
    const int tid = threadIdx.x;
    const int wid = tid >> 6, lane = tid & 63;
    const int l15 = lane & 15, quad = lane >> 4;
    const int bid = blockIdx.x;
    const int s = blockIdx.y;                 // kv-split index (0,1)
    const int qg = bid & 15, bh = bid >> 4;   // 16 q-groups consecutive -> L2 locality per bh
    const long base = ((long)(bh >> 4) * (T_*H_) + (bh & 15)) * 64;  // x-row order
    const unsigned short* Qp = Q + base;
    const unsigned short* Kp = K + base;
    const unsigned short* Vp = VT + (long)bh * 64 * 2048;   // [d][t]
    const int q0 = qg * 128 + wid * 32;
    const int kt0 = s * 16;                   // 16 key-tiles (64 keys) per split
    unsigned short* ps = &Ps[wid][0];
    const int rk  = (l15 >> 1) & 3;           // K read swizzle key (64B rows)
    const int rk3 = l15 & 7;                  // V read swizzle key (128B rows)
    const int sc8 = ((lane & 3) ^ ((lane >> 3) & 3)) * 8;   // K staged source chunk
    const int vt8 = ((lane & 7) ^ (lane >> 3)) * 8;         // V staged source t-chunk
    const int j16 = lane >> 2;                // K staging row within 16-row call
    const int vd8 = lane >> 3;                // V staging row within 8-row call

    // Q fragments (B-operand layout), pre-scaled by 1/8 (exact in bf16)
    s16x8 qf[2][2];
    #pragma unroll
    for (int qq = 0; qq < 2; ++qq)
        #pragma unroll
        for (int ks = 0; ks < 2; ++ks) {
            const s16x8 raw = *(const s16x8*)&Qp[(long)(q0 + qq*16 + l15)*1024 + ks*32 + quad*8];
            s16x8 q;
            #pragma unroll
            for (int j = 0; j < 8; ++j) q[j] = (short)f2b(b2f(raw[j]) * 0.125f);
            qf[qq][ks] = q;
        }

    s16x8 onef;
    #pragma unroll
    for (int j = 0; j < 8; ++j) onef[j] = (short)0x3F80;   // bf16 1.0

    f32x4 oacc[2][4] = {};
    f32x4 lacc[2] = {};

    // stage one 64-key tile: 16 x 1KB gl_lds calls, 4 per wave.
    auto stage = [&](int bufi, int kt) {
        char* kl = (char*)&Kbuf[bufi][0][0];
        char* vl = (char*)&Vbuf[bufi][0];
        const unsigned short* kg = Kp + (long)(kt*64) * 1024;
        const unsigned short* vg = Vp + kt*64;
        switch (wid) {
        case 0:   // K dhalf 0, j rows 0..63 (4 calls x 16 rows)
            #pragma unroll
            for (int c = 0; c < 4; ++c)
                gl_lds16(kg + (long)(c*16 + j16)*1024 + sc8,
                         kl + c*1024 + lane*16);
            break;
        case 1:   // K dhalf 1
            #pragma unroll
            for (int c = 0; c < 4; ++c)
                gl_lds16(kg + (long)(c*16 + j16)*1024 + 32 + sc8,
                         kl + 4096 + c*1024 + lane*16);
            break;
        case 2:   // V d rows 0..31 (4 calls x 8 rows of 128B)
            #pragma unroll
            for (int c = 0; c < 4; ++c)
                gl_lds16(vg + (long)(c*8 + vd8)*2048 + vt8,
                         vl + c*1024 + lane*16);
            break;
        default:  // V d rows 32..63
            #pragma unroll
            for (int c = 4; c < 8; ++c)
                gl_lds16(vg + (long)(c*8 + vd8)*2048 + vt8,
                         vl + c*1024 + lane*16);
            break;
        }
    };

    auto compute = [&](int bufi) {
        // S^T = K Q^T over 64 keys: A=K from LDS (swizzled), B=Q regs
        f32x4 sT[4][2] = {};
        #pragma unroll
        for (int ks = 0; ks < 2; ++ks)
            #pragma unroll
            for (int jt = 0; jt < 4; ++jt) {
                const s16x8 kf = *(const s16x8*)&Kbuf[bufi][ks][(jt*16 + l15)*32 + (quad ^ rk)*8];
                sT[jt][0] = mfma16(kf, qf[0][ks], sT[jt][0]);
                sT[jt][1] = mfma16(kf, qf[1][ks], sT[jt][1]);
            }
        // P = exp(S): pack 4 j-consecutive values -> b64 store to ps[q][j]
        #pragma unroll
        for (int jt = 0; jt < 4; ++jt)
            #pragma unroll
            for (int qq = 0; qq < 2; ++qq) {
                uint2 pk;
                pk.x = (unsigned int)f2b(__expf(sT[jt][qq][0]))
                     | ((unsigned int)f2b(__expf(sT[jt][qq][1])) << 16);
                pk.y = (unsigned int)f2b(__expf(sT[jt][qq][2]))
                     | ((unsigned int)f2b(__expf(sT[jt][qq][3])) << 16);
                *(uint2*)&ps[(qq*16 + l15)*72 + jt*16 + quad*4] = pk;
            }
        // O += P V ; l += P 1  (wave-private LDS, DS in-order per wave)
        s16x8 pf[2][2];
        #pragma unroll
        for (int qq = 0; qq < 2; ++qq)
            #pragma unroll
            for (int ks = 0; ks < 2; ++ks) {
                pf[qq][ks] = *(const s16x8*)&ps[(qq*16 + l15)*72 + ks*32 + quad*8];
                lacc[qq] = mfma16(pf[qq][ks], onef, lacc[qq]);
            }
        #pragma unroll
        for (int nt = 0; nt < 4; ++nt)
            #pragma unroll
            for (int ks = 0; ks < 2; ++ks) {
                const s16x8 vf = *(const s16x8*)&Vbuf[bufi][(nt*16 + l15)*64 + (((ks<<2)|quad) ^ rk3)*8];
                oacc[0][nt] = mfma16(pf[0][ks], vf, oacc[0][nt]);
                oacc[1][nt] = mfma16(pf[1][ks], vf, oacc[1][nt]);
            }
    };

    stage(0, kt0);
    for (int kt = 0; kt < 15; ++kt) {
        stage((kt + 1) & 1, kt0 + kt + 1);           // prefetch next tile (4 loads/wave)
        __builtin_amdgcn_s_waitcnt(WAIT_VM4);        // own 4 loads of tile kt landed
        __builtin_amdgcn_s_barrier();                // all waves' tile-kt loads landed
        __builtin_amdgcn_sched_barrier(0);
        compute(kt & 1);
        __builtin_amdgcn_s_barrier();                // buf kt&1 readers done before t+2 overwrite
        __builtin_amdgcn_sched_barrier(0);
    }
    __builtin_amdgcn_s_waitcnt(WAIT_VM0);
    __builtin_amdgcn_s_barrier();
    __builtin_amdgcn_sched_barrier(0);
    compute(1);   // kt = 15 (15 & 1 = 1)

    // epilogue: unnormalized O partial (bf16) + l partial (fp32).
    // Op layout [s][bh][t][d], lp layout [s][bh][t]; combined later.
    unsigned short* op = Op + ((long)s * 32 + bh) * 2048 * 64;
    float* lrow = lp + ((long)s * 32 + bh) * 2048;
    #pragma unroll
    for (int qq = 0; qq < 2; ++qq)
        #pragma unroll
        for (int r = 0; r < 4; ++r) {
            const int t = q0 + qq*16 + quad*4 + r;
            if (l15 == 0) lrow[t] = lacc[qq][r];
            #pragma unroll
            for (int nt = 0; nt < 4; ++nt)
                op[(long)t*64 + nt*16 + l15] = f2b(oacc[qq][nt][r]);
        }
}

// ---------------------------------------------------------------------------
// Kernel 2b (R3): combine kv-split partials: res = (O0+O1)/(l0+l1),
// written in x-row order [(b*T+t)*EMB + h*64 + d] for the Wproj GEMM.
// ---------------------------------------------------------------------------
__global__ __launch_bounds__(256) void attn_combine(const unsigned short* __restrict__ Op,
        const float* __restrict__ lp, unsigned short* __restrict__ res) {
    const int gid = blockIdx.x * 256 + threadIdx.x;
    const int row = gid >> 4;              // bh*2048 + t
    const int c4 = (gid & 15) * 4;
    const int bh = row >> 11, t = row & 2047;
    const int b = bh >> 4, h = bh & 15;
    const float inv = 1.f / (lp[row] + lp[ROWS + row]);
    const ushort4 u0 = *(const ushort4*)&Op[(long)row * 64 + c4];
    const ushort4 u1 = *(const ushort4*)&Op[((long)ROWS + row) * 64 + c4];
    unsigned short* r = res + ((long)(b*T_ + t)) * EMB + h*64 + c4;
    r[0] = f2b((b2f((short)u0.x) + b2f((short)u1.x)) * inv);
    r[1] = f2b((b2f((short)u0.y) + b2f((short)u1.y)) * inv);
    r[2] = f2b((b2f((short)u0.z) + b2f((short)u1.z)) * inv);
    r[3] = f2b((b2f((short)u0.w) + b2f((short)u1.w)) * inv);
}

// ---------------------------------------------------------------------------
// Kernel 3a (R10): bf16 MFMA GEMM, BK=64 two-buffer counted-vmcnt.
// 32 MFMA + 16 ds_read per barrier pair. 3-bit row-key swizzle, 128B rows.
// ---------------------------------------------------------------------------
__global__ __launch_bounds__(256) void gemm_gelu(const unsigned short* __restrict__ A,
        const unsigned short* __restrict__ Bt, const float* __restrict__ bias,
        unsigned short* __restrict__ C, int M, int N, int Kd) {
    __shared__ __align__(16) unsigned short As[2][128 * 64];
    __shared__ __align__(16) unsigned short Bs[2][128 * 64];
    const int tid = threadIdx.x;
    const int w = tid >> 6, lane = tid & 63;
    const int l15 = lane & 15, quad = lane >> 4;
    const int wm = w >> 1, wn = w & 1;
    const int bn = blockIdx.x, bm = blockIdx.y;
    const int sr8 = lane >> 3;                       // staged row within 8
    const int sk8 = ((lane & 7) ^ sr8) * 8;          // swizzled source k-chunk
    const int rk3 = l15 & 7;                         // read-side 3-bit key
    f32x4 acc[4][4] = {};

    auto stage = [&](int bi, int kt) {
        char* as = (char*)&As[bi][0];
        char* bs = (char*)&Bs[bi][0];
        #pragma unroll
        for (int c = 0; c < 4; ++c) {
            gl_lds16(A  + (long)(bm*128 + w*32 + c*8 + sr8)*Kd + kt + sk8,
                     as + (w*32 + c*8)*128 + lane*16);
            gl_lds16(Bt + (long)(bn*128 + w*32 + c*8 + sr8)*Kd + kt + sk8,
                     bs + (w*32 + c*8)*128 + lane*16);
        }
    };

    const int NT = Kd >> 6;
    stage(0, 0);
    int bi = 0;
    for (int t = 0; t < NT; ++t) {
        if (t + 1 < NT) {
            stage(bi ^ 1, (t + 1) * 64);             // prefetch next tile (8 loads)
            __builtin_amdgcn_s_waitcnt(WAIT_VM8);    // own tile-t 8 loads landed
        } else {
            __builtin_amdgcn_s_waitcnt(WAIT_VM0);
        }
        __builtin_amdgcn_s_barrier();                // all waves' tile-t loads landed
        __builtin_amdgcn_sched_barrier(0);
        #pragma unroll
        for (int ks = 0; ks < 2; ++ks) {
            s16x8 af[4], bf[4];
            #pragma unroll
            for (int mt = 0; mt < 4; ++mt)
                af[mt] = *(const s16x8*)&As[bi][(wm*64 + mt*16 + l15)*64 + (((ks<<2)|quad) ^ rk3)*8];
            #pragma unroll
            for (int nt = 0; nt < 4; ++nt)
                bf[nt] = *(const s16x8*)&Bs[bi][(wn*64 + nt*16 + l15)*64 + (((ks<<2)|quad) ^ rk3)*8];
            #pragma unroll
            for (int mt = 0; mt < 4; ++mt)
                #pragma unroll
                for (int nt = 0; nt < 4; ++nt)
                    acc[mt][nt] = mfma16(af[mt], bf[nt], acc[mt][nt]);
        }
        __builtin_amdgcn_s_barrier();                // readers done before overwrite
        __builtin_amdgcn_sched_barrier(0);
        bi ^= 1;
    }

    #pragma unroll
    for (int mt = 0; mt < 4; ++mt) {
        const int row0 = bm*128 + wm*64 + mt*16 + quad*4;
        #pragma unroll
        for (int nt = 0; nt < 4; ++nt) {
            const int col = bn*128 + wn*64 + nt*16 + l15;
            const float bv = bias[col];
            #pragma unroll
            for (int r = 0; r < 4; ++r) {
                float v = acc[mt][nt][r] + bv;
                v = 0.5f * v * (1.f + erff(v * 0.70710678118654752440f));
                C[(long)(row0 + r)*N + col] = f2b(v);
            }
        }
    }
}

// ---------------------------------------------------------------------------
// Kernel 3b (R10): split-K GEMM, same BK=64 structure as gemm_gelu.
// ---------------------------------------------------------------------------
__global__ __launch_bounds__(256) void gemm_splitk(const unsigned short* __restrict__ A,
        const unsigned short* __restrict__ Bt, P4 parts, int M, int N, int Kd, int Ks) {
    __shared__ __align__(16) unsigned short As[2][128 * 64];
    __shared__ __align__(16) unsigned short Bs[2][128 * 64];
    const int tid = threadIdx.x;
    const int w = tid >> 6, lane = tid & 63;
    const int l15 = lane & 15, quad = lane >> 4;
    const int wm = w >> 1, wn = w & 1;
    const int bn = blockIdx.x, bm = blockIdx.y, s = blockIdx.z;
    const int sr8 = lane >> 3;
    const int sk8 = ((lane & 7) ^ sr8) * 8;
    const int rk3 = l15 & 7;
    f32x4 acc[4][4] = {};
    const int k0 = s * Ks;

    auto stage = [&](int bi, int kt) {
        char* as = (char*)&As[bi][0];
        char* bs = (char*)&Bs[bi][0];
        #pragma unroll
        for (int c = 0; c < 4; ++c) {
            gl_lds16(A  + (long)(bm*128 + w*32 + c*8 + sr8)*Kd + kt + sk8,
                     as + (w*32 + c*8)*128 + lane*16);
            gl_lds16(Bt + (long)(bn*128 + w*32 + c*8 + sr8)*Kd + kt + sk8,
                     bs + (w*32 + c*8)*128 + lane*16);
        }
    };

    const int NT = Ks >> 6;
    stage(0, k0);
    int bi = 0;
    for (int t = 0; t < NT; ++t) {
        if (t + 1 < NT) {
            stage(bi ^ 1, k0 + (t + 1) * 64);
            __builtin_amdgcn_s_waitcnt(WAIT_VM8);
        } else {
            __builtin_amdgcn_s_waitcnt(WAIT_VM0);
        }
        __builtin_amdgcn_s_barrier();
        __builtin_amdgcn_sched_barrier(0);
        #pragma unroll
        for (int ks = 0; ks < 2; ++ks) {
            s16x8 af[4], bf[4];
            #pragma unroll
            for (int mt = 0; mt < 4; ++mt)
                af[mt] = *(const s16x8*)&As[bi][(wm*64 + mt*16 + l15)*64 + (((ks<<2)|quad) ^ rk3)*8];
            #pragma unroll
            for (int nt = 0; nt < 4; ++nt)
                bf[nt] = *(const s16x8*)&Bs[bi][(wn*64 + nt*16 + l15)*64 + (((ks<<2)|quad) ^ rk3)*8];
            #pragma unroll
            for (int mt = 0; mt < 4; ++mt)
                #pragma unroll
                for (int nt = 0; nt < 4; ++nt)
                    acc[mt][nt] = mfma16(af[mt], bf[nt], acc[mt][nt]);
        }
        __builtin_amdgcn_s_barrier();
        __builtin_amdgcn_sched_barrier(0);
        bi ^= 1;
    }

    unsigned short* Cp = parts.p[s];
    #pragma unroll
    for (int mt = 0; mt < 4; ++mt) {
        const int row0 = bm*128 + wm*64 + mt*16 + quad*4;
        #pragma unroll
        for (int nt = 0; nt < 4; ++nt) {
            const int col = bn*128 + wn*64 + nt*16 + l15;
            #pragma unroll
            for (int r = 0; r < 4; ++r)
                Cp[(long)(row0 + r)*N + col] = f2b(acc[mt][nt][r]);
        }
    }
}

// ---------------------------------------------------------------------------
// Kernel 4: out = LayerNorm(xa + sum(partials) [+ addb]) * g + b
// XBF: xa is bf16 (residual chain kept in bf16). Outputs optional.
// ---------------------------------------------------------------------------
template <int P, int XBF>
__global__ __launch_bounds__(256) void ln_kernel(const void* __restrict__ xa,
        P4 parts, const float* __restrict__ addb, const float* __restrict__ g,
        const float* __restrict__ bia, float* __restrict__ out,
        unsigned short* __restrict__ outb) {
    const int row = blockIdx.x;
    const int tid = threadIdx.x;
    float4 v;
    if (XBF) {
        const ushort4 u = ((const ushort4*)xa)[(long)row * (EMB/4) + tid];
        v.x = b2f((short)u.x); v.y = b2f((short)u.y);
        v.z = b2f((short)u.z); v.w = b2f((short)u.w);
    } else {
        v = ((const float4*)xa)[(long)row * (EMB/4) + tid];
    }
    #pragma unroll
    for (int p = 0; p < P; ++p) {
        const ushort4 u = ((const ushort4*)(parts.p[p] + (long)row * EMB))[tid];
        v.x += b2f((short)u.x); v.y += b2f((short)u.y);
        v.z += b2f((short)u.z); v.w += b2f((short)u.w);
    }
    if (addb) {
        const float4 ab = ((const float4*)addb)[tid];
        v.x += ab.x; v.y += ab.y; v.z += ab.z; v.w += ab.w;
    }
    float s = v.x + v.y + v.z + v.w;
    float ss = v.x * v.x + v.y * v.y + v.z * v.z + v.w * v.w;
    #pragma unroll
    for (int off = 32; off > 0; off >>= 1) {
        s += __shfl_down(s, off, 64);
        ss += __shfl_down(ss, off, 64);
    }
    __shared__ float ls[4], lss[4];
    __shared__ float mean_s, rstd_s;
    const int wid = tid >> 6, lane = tid & 63;
    if (lane == 0) { ls[wid] = s; lss[wid] = ss; }
    __syncthreads();
    if (tid == 0) {
        const float S0 = ls[0] + ls[1] + ls[2] + ls[3];
        const float S2 = lss[0] + lss[1] + lss[2] + lss[3];
        const float mean = S0 * (1.f / EMB);
        const float var = S2 * (1.f / EMB) - mean * mean;
        mean_s = mean;
        rstd_s = rsqrtf(var + 1e-5f);
    }
    __syncthreads();
    const float mean = mean_s, rstd = rstd_s;
    const float4 gg = ((const float4*)g)[tid];
    const float4 bb = ((const float4*)bia)[tid];
    float4 o;
    o.x = (v.x - mean) * rstd * gg.x + bb.x;
    o.y = (v.y - mean) * rstd * gg.y + bb.y;
    o.z = (v.z - mean) * rstd * gg.z + bb.z;
    o.w = (v.w - mean) * rstd * gg.w + bb.w;
    if (out) ((float4*)(out + (long)row * EMB))[tid] = o;
    if (outb) {
        unsigned short* ob = outb + (long)row * EMB + tid * 4;
        ob[0] = f2b(o.x); ob[1] = f2b(o.y); ob[2] = f2b(o.z); ob[3] = f2b(o.w);
    }
}

// ---------------------------------------------------------------------------
// Kernel 5: all weight transposes fused into one dispatch. 32x32 fp32->bf16.
// ---------------------------------------------------------------------------
__global__ __launch_bounds__(256) void transp_all(const float* __restrict__ Wp,
        const float* __restrict__ W1, const float* __restrict__ W2,
        const float* __restrict__ Wq, unsigned short* __restrict__ Wpt,
        unsigned short* __restrict__ W1t, unsigned short* __restrict__ W2t,
        unsigned short* __restrict__ Wqt) {
    int id = blockIdx.x;
    const float* W; unsigned short* Wt; int Kd, N, ntx;
    if (id < 1024)      {            W = Wp; Wt = Wpt; Kd = 1024; N = 1024; ntx = 32; }
    else if (id < 5120) { id -= 1024; W = W1; Wt = W1t; Kd = 1024; N = 4096; ntx = 128; }
    else if (id < 9216) { id -= 5120; W = W2; Wt = W2t; Kd = 4096; N = 1024; ntx = 32; }
    else                { id -= 9216; W = Wq; Wt = Wqt; Kd = 64;   N = 192;  ntx = 6;  }
    __shared__ float Ts[32][33];
    const int tid = threadIdx.x;
    const int n0 = (id % ntx) * 32, k0 = (id / ntx) * 32;
    const int r = tid >> 3, c4 = (tid & 7) * 4;
    const float4 v = *(const float4*)&W[(long)(k0 + r) * N + n0 + c4];
    Ts[r][c4] = v.x; Ts[r][c4 + 1] = v.y; Ts[r][c4 + 2] = v.z; Ts[r][c4 + 3] = v.w;
    __syncthreads();
    #pragma unroll
    for (int i = 0; i < 4; ++i)
        Wt[(long)(n0 + r) * Kd + k0 + c4 + i] = f2b(Ts[c4 + i][r]);
}

// ---------------------------------------------------------------------------
extern "C" void kernel_launch(void* const* d_in, const int* in_sizes, int n_in,
                              void* d_out, int out_size, void* d_ws, size_t ws_size,
                              hipStream_t stream) {
    (void)in_sizes; (void)n_in; (void)out_size; (void)ws_size;
    const float* x     = (const float*)d_in[0];
    const float* Wkqv  = (const float*)d_in[1];
    const float* Wproj = (const float*)d_in[2];
    const float* g1    = (const float*)d_in[3];
    const float* b1    = (const float*)d_in[4];
    const float* W1    = (const float*)d_in[5];
    const float* bff1  = (const float*)d_in[6];
    const float* W2    = (const float*)d_in[7];
    const float* bff2  = (const float*)d_in[8];
    const float* g2    = (const float*)d_in[9];
    const float* b2    = (const float*)d_in[10];
    float* out = (float*)d_out;
    char* ws = (char*)d_ws;

    // layout (MB offsets), 90 MB base envelope (proven in prior rounds):
    //  0.. 8 Qb -> x1b     8..40 Kb/Vb/resb -> hb
    // 40..48 VT (dead after attn) -> mp0/fp0   48..56 mp1/fp1
    // 48..64 Opb (attn partials, dead after combine; mp1 overwrites later)
    // 64..64.5 lpb   72..74 Wpt  74..82 W1t  82..90 W2t  90 Wqt
    const size_t MB = 1u << 20;
    unsigned short* Qb   = (unsigned short*)(ws + 0 * MB);
    unsigned short* Kb   = (unsigned short*)(ws + 8 * MB);
    unsigned short* Vb   = (unsigned short*)(ws + 16 * MB);
    unsigned short* resb = (unsigned short*)(ws + 24 * MB);
    unsigned short* hb   = (unsigned short*)(ws + 8 * MB);    // 32 MB (8..40)
    unsigned short* VTb  = (unsigned short*)(ws + 40 * MB);   // 8 MB
    unsigned short* mp0  = (unsigned short*)(ws + 40 * MB);
    unsigned short* mp1  = (unsigned short*)(ws + 48 * MB);
    unsigned short* Opb  = (unsigned short*)(ws + 48 * MB);   // 16 MB (48..64)
    float*          lpb  = (float*)         (ws + 64 * MB);   // 512 KB
    unsigned short* x1b  = Qb;
    unsigned short* Wpt  = (unsigned short*)(ws + 72 * MB);
    unsigned short* W1t  = (unsigned short*)(ws + 74 * MB);
    unsigned short* W2t  = (unsigned short*)(ws + 82 * MB);
    unsigned short* Wqt  = (unsigned short*)(ws + 90 * MB);

    // weight prep (single fused dispatch; every call - no persistent state)
    transp_all<<<dim3(9228), 256, 0, stream>>>(Wproj, W1, W2, Wkqv, Wpt, W1t, W2t, Wqt);

    // 1. kqv projection (MFMA, bf16 out, x-row order) + V transpose
    kqv_kernel<<<dim3(ROWS/128), 256, 0, stream>>>(x, Wqt, Kb, Qb, Vb);
    vt_kernel<<<dim3(T_/64, B_*H_), 256, 0, stream>>>(Vb, VTb);
    // 2. flash attention, 4-wave blocks, kv-split=2, KVBLK=64 -> 1024 blocks;
    //    partials combined exactly (no online max -> sums add)
    attn_kernel<<<dim3(512, 2), 256, 0, stream>>>(Qb, Kb, VTb, Opb, lpb);
    attn_combine<<<dim3(ROWS*16/256), 256, 0, stream>>>(Opb, lpb, resb);
    // 3. mha = res @ Wproj, split-K=2 (bf16 partials; summed in LN1)
    P4 mp; mp.p[0] = mp0; mp.p[1] = mp1; mp.p[2] = nullptr; mp.p[3] = nullptr;
    gemm_splitk<<<dim3(EMB/128, BT/128, 2), 256, 0, stream>>>(resb, Wpt, mp, BT, EMB, EMB, EMB/2);
    // 4. x1 = LN(x + mp0 + mp1)  (bf16 only)
    ln_kernel<2, 0><<<dim3(BT), 256, 0, stream>>>(x, mp, nullptr, g1, b1, nullptr, x1b);
    // 5. h = gelu(x1 @ W1 + bff1) (bf16 out)
    gemm_gelu<<<dim3(FF/128, BT/128), 256, 0, stream>>>(x1b, W1t, bff1, hb, BT, FF, EMB);
    // 6+7. ff = h @ W2 split-K=2 (NT=32 at BK=64), then final LN.
    P4 fp; fp.p[0] = mp0; fp.p[1] = mp1; fp.p[2] = nullptr; fp.p[3] = nullptr;
    gemm_splitk<<<dim3(EMB/128, BT/128, 2), 256, 0, stream>>>(hb, W2t, fp, BT, EMB, FF, FF/2);
    ln_kernel<2, 1><<<dim3(BT), 256, 0, stream>>>(x1b, fp, bff2, g2, b2, out, nullptr);
}

// Round 13
// 308.747 us; speedup vs baseline: 1.5874x; 1.0037x over previous
//
#include <hip/hip_runtime.h>
#include <hip/hip_bf16.h>
#include <math.h>

#define B_ 2
#define T_ 2048
#define H_ 16
#define S_ 64
#define EMB 1024
#define FF 4096
#define BT (B_*T_)        // 4096 rows
#define ROWS (B_*T_*H_)   // 65536

typedef __attribute__((ext_vector_type(8))) short s16x8;   // 8 bf16 (4 VGPRs)
typedef __attribute__((ext_vector_type(4))) float f32x4;   // MFMA C/D

struct P4 { unsigned short* p[4]; };   // partial-sum pointers (bf16)

__device__ __forceinline__ unsigned short f2b(float f) {
    return __builtin_bit_cast(unsigned short, __float2bfloat16(f));
}
__device__ __forceinline__ float b2f(short u) {
    return __builtin_bit_cast(float, ((unsigned int)(unsigned short)u) << 16);
}

// async global->LDS, 16B per lane (LDS dest = wave-uniform base + lane*16;
// GLOBAL address may be fully per-lane - only the LDS side is constrained)
__device__ __forceinline__ void gl_lds16(const void* g, void* l) {
    __builtin_amdgcn_global_load_lds(
        (const __attribute__((address_space(1))) void*)g,
        (__attribute__((address_space(3))) void*)l, 16, 0, 0);
}

__device__ __forceinline__ f32x4 mfma16(s16x8 a, s16x8 b, f32x4 c) {
    return __builtin_amdgcn_mfma_f32_16x16x32_bf16(a, b, c, 0, 0, 0);
}

// s_waitcnt simm16 (gfx9): vmcnt[3:0]|hi[15:14], expcnt[6:4], lgkmcnt[11:8]
#define WAIT_VM8 0x0F78   // vmcnt(8)
#define WAIT_VM4 0x0F74   // vmcnt(4)
#define WAIT_VM2 0x0F72   // vmcnt(2)
#define WAIT_VM0 0x0F70   // vmcnt(0)

// LDS swizzles (rule #21: linear gl_lds dest + inverse-permuted GLOBAL
// source + same-permuted read):
//  64B rows (K tiles):  2-bit key, read chunk = quad ^ ((l15>>1)&3),
//                       staged source chunk = (lane&3)^((lane>>3)&3).
//  128B rows (GEMM/V):  3-bit key, read chunk = c ^ (l15&7),
//                       staged source chunk = (lane&7)^(lane>>3).
// Both verified conflict-free (R6/R10: SQ_LDS_BANK_CONFLICT = 0).

// ---------------------------------------------------------------------------
// Kernel 1: kqv, MFMA version. x [ROWS][64] fp32, Wqt [192][64] bf16.
// Outputs K,Q,V bf16 in x-row order: [ (b*T+t)*H+h ][64].
// ---------------------------------------------------------------------------
__global__ __launch_bounds__(256) void kqv_kernel(const float* __restrict__ x,
        const unsigned short* __restrict__ Wqt, unsigned short* __restrict__ K,
        unsigned short* __restrict__ Q, unsigned short* __restrict__ V) {
    const int tid = threadIdx.x;
    const int w = tid >> 6, lane = tid & 63;
    const int l15 = lane & 15, quad = lane >> 4;
    const long r0 = (long)blockIdx.x * 128 + w * 32;

    s16x8 af[2][2];
    #pragma unroll
    for (int mt = 0; mt < 2; ++mt)
        #pragma unroll
        for (int ks = 0; ks < 2; ++ks) {
            const float* xp = x + (r0 + mt*16 + l15) * 64 + ks*32 + quad*8;
            const float4 v0 = *(const float4*)xp;
            const float4 v1 = *(const float4*)(xp + 4);
            s16x8 a;
            a[0] = (short)f2b(v0.x); a[1] = (short)f2b(v0.y);
            a[2] = (short)f2b(v0.z); a[3] = (short)f2b(v0.w);
            a[4] = (short)f2b(v1.x); a[5] = (short)f2b(v1.y);
            a[6] = (short)f2b(v1.z); a[7] = (short)f2b(v1.w);
            af[mt][ks] = a;
        }

    #pragma unroll
    for (int nt = 0; nt < 12; ++nt) {
        const s16x8 b0 = *(const s16x8*)&Wqt[(nt*16 + l15)*64 + quad*8];
        const s16x8 b1 = *(const s16x8*)&Wqt[(nt*16 + l15)*64 + 32 + quad*8];
        f32x4 acc[2] = {};
        #pragma unroll
        for (int mt = 0; mt < 2; ++mt) {
            acc[mt] = mfma16(af[mt][0], b0, acc[mt]);
            acc[mt] = mfma16(af[mt][1], b1, acc[mt]);
        }
        unsigned short* dst = (nt < 4) ? K : (nt < 8) ? Q : V;
        const int c0 = (nt & 3) * 16 + l15;
        #pragma unroll
        for (int mt = 0; mt < 2; ++mt)
            #pragma unroll
            for (int r = 0; r < 4; ++r)
                dst[(r0 + mt*16 + quad*4 + r) * 64 + c0] = f2b(acc[mt][r]);
    }
}

// ---------------------------------------------------------------------------
// Kernel 1b: V [ (b,t,h) ][d] -> VT [bh][d][t]  (64x64 tiles per (b,h))
// ---------------------------------------------------------------------------
__global__ __launch_bounds__(256) void vt_kernel(const unsigned short* __restrict__ V,
        unsigned short* __restrict__ VT) {
    __shared__ unsigned short Ts[64][72];
    const int tid = threadIdx.x;
    const int tt = blockIdx.x, bh = blockIdx.y;
    const int b = bh >> 4, h = bh & 15;
    const long vbase = ((long)b * (T_*H_) + h) * 64;   // + t*1024 + d
    #pragma unroll
    for (int i = 0; i < 2; ++i) {
        const int id = i * 256 + tid;          // 0..511
        const int tr = id >> 3, dc = (id & 7) * 8;
        const s16x8 v = *(const s16x8*)&V[vbase + (long)(tt*64 + tr)*1024 + dc];
        *(s16x8*)&Ts[tr][dc] = v;
    }
    __syncthreads();
    #pragma unroll
    for (int i = 0; i < 2; ++i) {
        const int id = i * 256 + tid;
        const int d = id >> 3, tc = (id & 7) * 8;
        s16x8 o;
        #pragma unroll
        for (int j = 0; j < 8; ++j) o[j] = (short)Ts[tc + j][d];
        *(s16x8*)&VT[((long)bh*64 + d)*2048 + tt*64 + tc] = o;
    }
}

// ---------------------------------------------------------------------------
// Kernel 2 (R11): flash attention, 4-wave blocks, kv-split=2, KVBLK=64.
// K rows 64B (2-bit swizzle), V rows 128B (3-bit swizzle). Ps stride 72.
// ---------------------------------------------------------------------------
__global__ __launch_bounds__(256) void attn_kernel(const unsigned short* __restrict__ Q,
        const unsigned short* __restrict__ K, const unsigned short* __restrict__ VT,
        unsigned short* __restrict__ Op, float* __restrict__ lp) {
    __shared__ __align__(16) unsigned short Kbuf[2][2][64*32];  // [buf][dhalf][j64][d32]
    __shared__ __align__(16) unsigned short Vbuf[2][64*64];     // [buf][d][t64]
    __shared__ __align__(16) unsigned short Ps[4][32*72];       // per-wave [q][j64], pad 72
    const int tid = threadIdx.x;
    const int wid = tid >> 6, lane = tid & 63;
    const int l15 = lane & 15, quad = lane >> 4;
    const int bid = blockIdx.x;
    const int s = blockIdx.y;                 // kv-split index (0,1)
    const int qg = bid & 15, bh = bid >> 4;   // 16 q-groups consecutive -> L2 locality per bh
    const long base = ((long)(bh >> 4) * (T_*H_) + (bh & 15)) * 64;  // x-row order
    const unsigned short* Qp = Q + base;
    const unsigned short* Kp = K + base;
    const unsigned short* Vp = VT + (long)bh * 64 * 2048;   // [d][t]
    const int q0 = qg * 128 + wid * 32;
    const int kt0 = s * 16;                   // 16 key-tiles (64 keys) per split
    unsigned short* ps = &Ps[wid][0];
    const int rk  = (l15 >> 1) & 3;           // K read swizzle key (64B rows)
    const int rk3 = l15 & 7;                  // V read swizzle key (128B rows)
    const int sc8 = ((lane & 3) ^ ((lane >> 3) & 3)) * 8;   // K staged source chunk
    const int vt8 = ((lane & 7) ^ (lane >> 3)) * 8;         // V staged source t-chunk
    const int j16 = lane >> 2;                // K staging row within 16-row call
    const int vd8 = lane >> 3;                // V staging row within 8-row call

    // Q fragments (B-operand layout), pre-scaled by 1/8 (exact in bf16)
    s16x8 qf[2][2];
    #pragma unroll
    for (int qq = 0; qq < 2; ++qq)
        #pragma unroll
        for (int ks = 0; ks < 2; ++ks) {
            const s16x8 raw = *(const s16x8*)&Qp[(long)(q0 + qq*16 + l15)*1024 + ks*32 + quad*8];
            s16x8 q;
            #pragma unroll
            for (int j = 0; j < 8; ++j) q[j] = (short)f2b(b2f(raw[j]) * 0.125f);
            qf[qq][ks] = q;
        }

    s16x8 onef;
    #pragma unroll
    for (int j = 0; j < 8; ++j) onef[j] = (short)0x3F80;   // bf16 1.0

    f32x4 oacc[2][4] = {};
    f32x4 lacc[2] = {};

    // stage one 64-key tile: 16 x 1KB gl_lds calls, 4 per wave.
    auto stage = [&](int bufi, int kt) {
        char* kl = (char*)&Kbuf[bufi][0][0];
        char* vl = (char*)&Vbuf[bufi][0];
        const unsigned short* kg = Kp + (long)(kt*64) * 1024;
        const unsigned short* vg = Vp + kt*64;
        switch (wid) {
        case 0:   // K dhalf 0, j rows 0..63 (4 calls x 16 rows)
            #pragma unroll
            for (int c = 0; c < 4; ++c)
                gl_lds16(kg + (long)(c*16 + j16)*1024 + sc8,
                         kl + c*1024 + lane*16);
            break;
        case 1:   // K dhalf 1
            #pragma unroll
            for (int c = 0; c < 4; ++c)
                gl_lds16(kg + (long)(c*16 + j16)*1024 + 32 + sc8,
                         kl + 4096 + c*1024 + lane*16);
            break;
        case 2:   // V d rows 0..31 (4 calls x 8 rows of 128B)
            #pragma unroll
            for (int c = 0; c < 4; ++c)
                gl_lds16(vg + (long)(c*8 + vd8)*2048 + vt8,
                         vl + c*1024 + lane*16);
            break;
        default:  // V d rows 32..63
            #pragma unroll
            for (int c = 4; c < 8; ++c)
                gl_lds16(vg + (long)(c*8 + vd8)*2048 + vt8,
                         vl + c*1024 + lane*16);
            break;
        }
    };

    auto compute = [&](int bufi) {
        // S^T = K Q^T over 64 keys: A=K from LDS (swizzled), B=Q regs
        f32x4 sT[4][2] = {};
        #pragma unroll
        for (int ks = 0; ks < 2; ++ks)
            #pragma unroll
            for (int jt = 0; jt < 4; ++jt) {
                const s16x8 kf = *(const s16x8*)&Kbuf[bufi][ks][(jt*16 + l15)*32 + (quad ^ rk)*8];
                sT[jt][0] = mfma16(kf, qf[0][ks], sT[jt][0]);
                sT[jt][1] = mfma16(kf, qf[1][ks], sT[jt][1]);
            }
        // P = exp(S): pack 4 j-consecutive values -> b64 store to ps[q][j]
        #pragma unroll
        for (int jt = 0; jt < 4; ++jt)
            #pragma unroll
            for (int qq = 0; qq < 2; ++qq) {
                uint2 pk;
                pk.x = (unsigned int)f2b(__expf(sT[jt][qq][0]))
                     | ((unsigned int)f2b(__expf(sT[jt][qq][1])) << 16);
                pk.y = (unsigned int)f2b(__expf(sT[jt][qq][2]))
                     | ((unsigned int)f2b(__expf(sT[jt][qq][3])) << 16);
                *(uint2*)&ps[(qq*16 + l15)*72 + jt*16 + quad*4] = pk;
            }
        // O += P V ; l += P 1  (wave-private LDS, DS in-order per wave)
        s16x8 pf[2][2];
        #pragma unroll
        for (int qq = 0; qq < 2; ++qq)
            #pragma unroll
            for (int ks = 0; ks < 2; ++ks) {
                pf[qq][ks] = *(const s16x8*)&ps[(qq*16 + l15)*72 + ks*32 + quad*8];
                lacc[qq] = mfma16(pf[qq][ks], onef, lacc[qq]);
            }
        #pragma unroll
        for (int nt = 0; nt < 4; ++nt)
            #pragma unroll
            for (int ks = 0; ks < 2; ++ks) {
                const s16x8 vf = *(const s16x8*)&Vbuf[bufi][(nt*16 + l15)*64 + (((ks<<2)|quad) ^ rk3)*8];
                oacc[0][nt] = mfma16(pf[0][ks], vf, oacc[0][nt]);
                oacc[1][nt] = mfma16(pf[1][ks], vf, oacc[1][nt]);
            }
    };

    stage(0, kt0);
    for (int kt = 0; kt < 15; ++kt) {
        stage((kt + 1) & 1, kt0 + kt + 1);           // prefetch next tile (4 loads/wave)
        __builtin_amdgcn_s_waitcnt(WAIT_VM4);        // own 4 loads of tile kt landed
        __builtin_amdgcn_s_barrier();                // all waves' tile-kt loads landed
        __builtin_amdgcn_sched_barrier(0);
        compute(kt & 1);
        __builtin_amdgcn_s_barrier();                // buf kt&1 readers done before t+2 overwrite
        __builtin_amdgcn_sched_barrier(0);
    }
    __builtin_amdgcn_s_waitcnt(WAIT_VM0);
    __builtin_amdgcn_s_barrier();
    __builtin_amdgcn_sched_barrier(0);
    compute(1);   // kt = 15 (15 & 1 = 1)

    // epilogue: unnormalized O partial (bf16) + l partial (fp32).
    // Op layout [s][bh][t][d], lp layout [s][bh][t]; combined later.
    unsigned short* op = Op + ((long)s * 32 + bh) * 2048 * 64;
    float* lrow = lp + ((long)s * 32 + bh) * 2048;
    #pragma unroll
    for (int qq = 0; qq < 2; ++qq)
        #pragma unroll
        for (int r = 0; r < 4; ++r) {
            const int t = q0 + qq*16 + quad*4 + r;
            if (l15 == 0) lrow[t] = lacc[qq][r];
            #pragma unroll
            for (int nt = 0; nt < 4; ++nt)
                op[(long)t*64 + nt*16 + l15] = f2b(oacc[qq][nt][r]);
        }
}

// ---------------------------------------------------------------------------
// Kernel 2b (R3): combine kv-split partials: res = (O0+O1)/(l0+l1),
// written in x-row order [(b*T+t)*EMB + h*64 + d] for the Wproj GEMM.
// ---------------------------------------------------------------------------
__global__ __launch_bounds__(256) void attn_combine(const unsigned short* __restrict__ Op,
        const float* __restrict__ lp, unsigned short* __restrict__ res) {
    const int gid = blockIdx.x * 256 + threadIdx.x;
    const int row = gid >> 4;              // bh*2048 + t
    const int c4 = (gid & 15) * 4;
    const int bh = row >> 11, t = row & 2047;
    const int b = bh >> 4, h = bh & 15;
    const float inv = 1.f / (lp[row] + lp[ROWS + row]);
    const ushort4 u0 = *(const ushort4*)&Op[(long)row * 64 + c4];
    const ushort4 u1 = *(const ushort4*)&Op[((long)ROWS + row) * 64 + c4];
    unsigned short* r = res + ((long)(b*T_ + t)) * EMB + h*64 + c4;
    r[0] = f2b((b2f((short)u0.x) + b2f((short)u1.x)) * inv);
    r[1] = f2b((b2f((short)u0.y) + b2f((short)u1.y)) * inv);
    r[2] = f2b((b2f((short)u0.z) + b2f((short)u1.z)) * inv);
    r[3] = f2b((b2f((short)u0.w) + b2f((short)u1.w)) * inv);
}

// ---------------------------------------------------------------------------
// Kernel 3a (R12): bf16 MFMA GEMM, 256x256 tile, 8 waves (512 thr), BK=64.
// Third application of the amortization lever (R9 split-2, R10 BK=64):
// per wave per barrier-pair: 64 MFMA + 24 ds_read (2x work, 1.5x reads -
// reuse af[8]+bf[4]); SAME counted-vmcnt protocol and constants as R10
// (8 gl_lds/wave/tile -> WAIT_VM8). LDS 128KB -> 1 block/CU, 8 waves.
// Grid 16x16 = 256 blocks = exactly 1 per CU. Swizzle identical to R10.
// ---------------------------------------------------------------------------
__global__ __launch_bounds__(512) void gemm_gelu(const unsigned short* __restrict__ A,
        const unsigned short* __restrict__ Bt, const float* __restrict__ bias,
        unsigned short* __restrict__ C, int M, int N, int Kd) {
    __shared__ __align__(16) unsigned short As[2][256 * 64];
    __shared__ __align__(16) unsigned short Bs[2][256 * 64];
    const int tid = threadIdx.x;
    const int w = tid >> 6, lane = tid & 63;
    const int l15 = lane & 15, quad = lane >> 4;
    const int wm = w >> 2, wn = w & 3;               // 2M x 4N wave grid
    const int bn = blockIdx.x, bm = blockIdx.y;
    const int sr8 = lane >> 3;                       // staged row within 8
    const int sk8 = ((lane & 7) ^ sr8) * 8;          // swizzled source k-chunk
    const int rk3 = l15 & 7;                         // read-side 3-bit key
    f32x4 acc[8][4] = {};

    auto stage = [&](int bi, int kt) {
        char* as = (char*)&As[bi][0];
        char* bs = (char*)&Bs[bi][0];
        #pragma unroll
        for (int c = 0; c < 4; ++c) {
            gl_lds16(A  + (long)(bm*256 + w*32 + c*8 + sr8)*Kd + kt + sk8,
                     as + (w*32 + c*8)*128 + lane*16);
            gl_lds16(Bt + (long)(bn*256 + w*32 + c*8 + sr8)*Kd + kt + sk8,
                     bs + (w*32 + c*8)*128 + lane*16);
        }
    };

    const int NT = Kd >> 6;
    stage(0, 0);
    int bi = 0;
    for (int t = 0; t < NT; ++t) {
        if (t + 1 < NT) {
            stage(bi ^ 1, (t + 1) * 64);             // prefetch next tile (8 loads)
            __builtin_amdgcn_s_waitcnt(WAIT_VM8);    // own tile-t 8 loads landed
        } else {
            __builtin_amdgcn_s_waitcnt(WAIT_VM0);
        }
        __builtin_amdgcn_s_barrier();                // all waves' tile-t loads landed
        __builtin_amdgcn_sched_barrier(0);
        #pragma unroll
        for (int ks = 0; ks < 2; ++ks) {
            s16x8 af[8], bf[4];
            #pragma unroll
            for (int mt = 0; mt < 8; ++mt)
                af[mt] = *(const s16x8*)&As[bi][(wm*128 + mt*16 + l15)*64 + (((ks<<2)|quad) ^ rk3)*8];
            #pragma unroll
            for (int nt = 0; nt < 4; ++nt)
                bf[nt] = *(const s16x8*)&Bs[bi][(wn*64 + nt*16 + l15)*64 + (((ks<<2)|quad) ^ rk3)*8];
            #pragma unroll
            for (int mt = 0; mt < 8; ++mt)
                #pragma unroll
                for (int nt = 0; nt < 4; ++nt)
                    acc[mt][nt] = mfma16(af[mt], bf[nt], acc[mt][nt]);
        }
        __builtin_amdgcn_s_barrier();                // readers done before overwrite
        __builtin_amdgcn_sched_barrier(0);
        bi ^= 1;
    }

    #pragma unroll
    for (int mt = 0; mt < 8; ++mt) {
        const int row0 = bm*256 + wm*128 + mt*16 + quad*4;
        #pragma unroll
        for (int nt = 0; nt < 4; ++nt) {
            const int col = bn*256 + wn*64 + nt*16 + l15;
            const float bv = bias[col];
            #pragma unroll
            for (int r = 0; r < 4; ++r) {
                float v = acc[mt][nt][r] + bv;
                v = 0.5f * v * (1.f + erff(v * 0.70710678118654752440f));
                C[(long)(row0 + r)*N + col] = f2b(v);
            }
        }
    }
}

// ---------------------------------------------------------------------------
// Kernel 3b (R10): split-K GEMM, 128x128 BK=64 two-buffer counted-vmcnt.
// (N=1024 outputs are too narrow for the 256^2 tile - grid would idle
// half the CUs - so splitk keeps the R10 geometry.)
// ---------------------------------------------------------------------------
__global__ __launch_bounds__(256) void gemm_splitk(const unsigned short* __restrict__ A,
        const unsigned short* __restrict__ Bt, P4 parts, int M, int N, int Kd, int Ks) {
    __shared__ __align__(16) unsigned short As[2][128 * 64];
    __shared__ __align__(16) unsigned short Bs[2][128 * 64];
    const int tid = threadIdx.x;
    const int w = tid >> 6, lane = tid & 63;
    const int l15 = lane & 15, quad = lane >> 4;
    const int wm = w >> 1, wn = w & 1;
    const int bn = blockIdx.x, bm = blockIdx.y, s = blockIdx.z;
    const int sr8 = lane >> 3;
    const int sk8 = ((lane & 7) ^ sr8) * 8;
    const int rk3 = l15 & 7;
    f32x4 acc[4][4] = {};
    const int k0 = s * Ks;

    auto stage = [&](int bi, int kt) {
        char* as = (char*)&As[bi][0];
        char* bs = (char*)&Bs[bi][0];
        #pragma unroll
        for (int c = 0; c < 4; ++c) {
            gl_lds16(A  + (long)(bm*128 + w*32 + c*8 + sr8)*Kd + kt + sk8,
                     as + (w*32 + c*8)*128 + lane*16);
            gl_lds16(Bt + (long)(bn*128 + w*32 + c*8 + sr8)*Kd + kt + sk8,
                     bs + (w*32 + c*8)*128 + lane*16);
        }
    };

    const int NT = Ks >> 6;
    stage(0, k0);
    int bi = 0;
    for (int t = 0; t < NT; ++t) {
        if (t + 1 < NT) {
            stage(bi ^ 1, k0 + (t + 1) * 64);
            __builtin_amdgcn_s_waitcnt(WAIT_VM8);
        } else {
            __builtin_amdgcn_s_waitcnt(WAIT_VM0);
        }
        __builtin_amdgcn_s_barrier();
        __builtin_amdgcn_sched_barrier(0);
        #pragma unroll
        for (int ks = 0; ks < 2; ++ks) {
            s16x8 af[4], bf[4];
            #pragma unroll
            for (int mt = 0; mt < 4; ++mt)
                af[mt] = *(const s16x8*)&As[bi][(wm*64 + mt*16 + l15)*64 + (((ks<<2)|quad) ^ rk3)*8];
            #pragma unroll
            for (int nt = 0; nt < 4; ++nt)
                bf[nt] = *(const s16x8*)&Bs[bi][(wn*64 + nt*16 + l15)*64 + (((ks<<2)|quad) ^ rk3)*8];
            #pragma unroll
            for (int mt = 0; mt < 4; ++mt)
                #pragma unroll
                for (int nt = 0; nt < 4; ++nt)
                    acc[mt][nt] = mfma16(af[mt], bf[nt], acc[mt][nt]);
        }
        __builtin_amdgcn_s_barrier();
        __builtin_amdgcn_sched_barrier(0);
        bi ^= 1;
    }

    unsigned short* Cp = parts.p[s];
    #pragma unroll
    for (int mt = 0; mt < 4; ++mt) {
        const int row0 = bm*128 + wm*64 + mt*16 + quad*4;
        #pragma unroll
        for (int nt = 0; nt < 4; ++nt) {
            const int col = bn*128 + wn*64 + nt*16 + l15;
            #pragma unroll
            for (int r = 0; r < 4; ++r)
                Cp[(long)(row0 + r)*N + col] = f2b(acc[mt][nt][r]);
        }
    }
}

// ---------------------------------------------------------------------------
// Kernel 4: out = LayerNorm(xa + sum(partials) [+ addb]) * g + b
// XBF: xa is bf16 (residual chain kept in bf16). Outputs optional.
// ---------------------------------------------------------------------------
template <int P, int XBF>
__global__ __launch_bounds__(256) void ln_kernel(const void* __restrict__ xa,
        P4 parts, const float* __restrict__ addb, const float* __restrict__ g,
        const float* __restrict__ bia, float* __restrict__ out,
        unsigned short* __restrict__ outb) {
    const int row = blockIdx.x;
    const int tid = threadIdx.x;
    float4 v;
    if (XBF) {
        const ushort4 u = ((const ushort4*)xa)[(long)row * (EMB/4) + tid];
        v.x = b2f((short)u.x); v.y = b2f((short)u.y);
        v.z = b2f((short)u.z); v.w = b2f((short)u.w);
    } else {
        v = ((const float4*)xa)[(long)row * (EMB/4) + tid];
    }
    #pragma unroll
    for (int p = 0; p < P; ++p) {
        const ushort4 u = ((const ushort4*)(parts.p[p] + (long)row * EMB))[tid];
        v.x += b2f((short)u.x); v.y += b2f((short)u.y);
        v.z += b2f((short)u.z); v.w += b2f((short)u.w);
    }
    if (addb) {
        const float4 ab = ((const float4*)addb)[tid];
        v.x += ab.x; v.y += ab.y; v.z += ab.z; v.w += ab.w;
    }
    float s = v.x + v.y + v.z + v.w;
    float ss = v.x * v.x + v.y * v.y + v.z * v.z + v.w * v.w;
    #pragma unroll
    for (int off = 32; off > 0; off >>= 1) {
        s += __shfl_down(s, off, 64);
        ss += __shfl_down(ss, off, 64);
    }
    __shared__ float ls[4], lss[4];
    __shared__ float mean_s, rstd_s;
    const int wid = tid >> 6, lane = tid & 63;
    if (lane == 0) { ls[wid] = s; lss[wid] = ss; }
    __syncthreads();
    if (tid == 0) {
        const float S0 = ls[0] + ls[1] + ls[2] + ls[3];
        const float S2 = lss[0] + lss[1] + lss[2] + lss[3];
        const float mean = S0 * (1.f / EMB);
        const float var = S2 * (1.f / EMB) - mean * mean;
        mean_s = mean;
        rstd_s = rsqrtf(var + 1e-5f);
    }
    __syncthreads();
    const float mean = mean_s, rstd = rstd_s;
    const float4 gg = ((const float4*)g)[tid];
    const float4 bb = ((const float4*)bia)[tid];
    float4 o;
    o.x = (v.x - mean) * rstd * gg.x + bb.x;
    o.y = (v.y - mean) * rstd * gg.y + bb.y;
    o.z = (v.z - mean) * rstd * gg.z + bb.z;
    o.w = (v.w - mean) * rstd * gg.w + bb.w;
    if (out) ((float4*)(out + (long)row * EMB))[tid] = o;
    if (outb) {
        unsigned short* ob = outb + (long)row * EMB + tid * 4;
        ob[0] = f2b(o.x); ob[1] = f2b(o.y); ob[2] = f2b(o.z); ob[3] = f2b(o.w);
    }
}

// ---------------------------------------------------------------------------
// Kernel 5: all weight transposes fused into one dispatch. 32x32 fp32->bf16.
// ---------------------------------------------------------------------------
__global__ __launch_bounds__(256) void transp_all(const float* __restrict__ Wp,
        const float* __restrict__ W1, const float* __restrict__ W2,
        const float* __restrict__ Wq, unsigned short* __restrict__ Wpt,
        unsigned short* __restrict__ W1t, unsigned short* __restrict__ W2t,
        unsigned short* __restrict__ Wqt) {
    int id = blockIdx.x;
    const float* W; unsigned short* Wt; int Kd, N, ntx;
    if (id < 1024)      {            W = Wp; Wt = Wpt; Kd = 1024; N = 1024; ntx = 32; }
    else if (id < 5120) { id -= 1024; W = W1; Wt = W1t; Kd = 1024; N = 4096; ntx = 128; }
    else if (id < 9216) { id -= 5120; W = W2; Wt = W2t; Kd = 4096; N = 1024; ntx = 32; }
    else                { id -= 9216; W = Wq; Wt = Wqt; Kd = 64;   N = 192;  ntx = 6;  }
    __shared__ float Ts[32][33];
    const int tid = threadIdx.x;
    const int n0 = (id % ntx) * 32, k0 = (id / ntx) * 32;
    const int r = tid >> 3, c4 = (tid & 7) * 4;
    const float4 v = *(const float4*)&W[(long)(k0 + r) * N + n0 + c4];
    Ts[r][c4] = v.x; Ts[r][c4 + 1] = v.y; Ts[r][c4 + 2] = v.z; Ts[r][c4 + 3] = v.w;
    __syncthreads();
    #pragma unroll
    for (int i = 0; i < 4; ++i)
        Wt[(long)(n0 + r) * Kd + k0 + c4 + i] = f2b(Ts[c4 + i][r]);
}

// ---------------------------------------------------------------------------
extern "C" void kernel_launch(void* const* d_in, const int* in_sizes, int n_in,
                              void* d_out, int out_size, void* d_ws, size_t ws_size,
                              hipStream_t stream) {
    (void)in_sizes; (void)n_in; (void)out_size; (void)ws_size;
    const float* x     = (const float*)d_in[0];
    const float* Wkqv  = (const float*)d_in[1];
    const float* Wproj = (const float*)d_in[2];
    const float* g1    = (const float*)d_in[3];
    const float* b1    = (const float*)d_in[4];
    const float* W1    = (const float*)d_in[5];
    const float* bff1  = (const float*)d_in[6];
    const float* W2    = (const float*)d_in[7];
    const float* bff2  = (const float*)d_in[8];
    const float* g2    = (const float*)d_in[9];
    const float* b2    = (const float*)d_in[10];
    float* out = (float*)d_out;
    char* ws = (char*)d_ws;

    // layout (MB offsets), 90 MB base envelope (proven in prior rounds):
    //  0.. 8 Qb -> x1b     8..40 Kb/Vb/resb -> hb
    // 40..48 VT (dead after attn) -> mp0/fp0   48..56 mp1/fp1
    // 48..64 Opb (attn partials, dead after combine; mp1 overwrites later)
    // 64..64.5 lpb   72..74 Wpt  74..82 W1t  82..90 W2t  90 Wqt
    const size_t MB = 1u << 20;
    unsigned short* Qb   = (unsigned short*)(ws + 0 * MB);
    unsigned short* Kb   = (unsigned short*)(ws + 8 * MB);
    unsigned short* Vb   = (unsigned short*)(ws + 16 * MB);
    unsigned short* resb = (unsigned short*)(ws + 24 * MB);
    unsigned short* hb   = (unsigned short*)(ws + 8 * MB);    // 32 MB (8..40)
    unsigned short* VTb  = (unsigned short*)(ws + 40 * MB);   // 8 MB
    unsigned short* mp0  = (unsigned short*)(ws + 40 * MB);
    unsigned short* mp1  = (unsigned short*)(ws + 48 * MB);
    unsigned short* Opb  = (unsigned short*)(ws + 48 * MB);   // 16 MB (48..64)
    float*          lpb  = (float*)         (ws + 64 * MB);   // 512 KB
    unsigned short* x1b  = Qb;
    unsigned short* Wpt  = (unsigned short*)(ws + 72 * MB);
    unsigned short* W1t  = (unsigned short*)(ws + 74 * MB);
    unsigned short* W2t  = (unsigned short*)(ws + 82 * MB);
    unsigned short* Wqt  = (unsigned short*)(ws + 90 * MB);

    // weight prep (single fused dispatch; every call - no persistent state)
    transp_all<<<dim3(9228), 256, 0, stream>>>(Wproj, W1, W2, Wkqv, Wpt, W1t, W2t, Wqt);

    // 1. kqv projection (MFMA, bf16 out, x-row order) + V transpose
    kqv_kernel<<<dim3(ROWS/128), 256, 0, stream>>>(x, Wqt, Kb, Qb, Vb);
    vt_kernel<<<dim3(T_/64, B_*H_), 256, 0, stream>>>(Vb, VTb);
    // 2. flash attention, 4-wave blocks, kv-split=2, KVBLK=64 -> 1024 blocks;
    //    partials combined exactly (no online max -> sums add)
    attn_kernel<<<dim3(512, 2), 256, 0, stream>>>(Qb, Kb, VTb, Opb, lpb);
    attn_combine<<<dim3(ROWS*16/256), 256, 0, stream>>>(Opb, lpb, resb);
    // 3. mha = res @ Wproj, split-K=2 (bf16 partials; summed in LN1)
    P4 mp; mp.p[0] = mp0; mp.p[1] = mp1; mp.p[2] = nullptr; mp.p[3] = nullptr;
    gemm_splitk<<<dim3(EMB/128, BT/128, 2), 256, 0, stream>>>(resb, Wpt, mp, BT, EMB, EMB, EMB/2);
    // 4. x1 = LN(x + mp0 + mp1)  (bf16 only)
    ln_kernel<2, 0><<<dim3(BT), 256, 0, stream>>>(x, mp, nullptr, g1, b1, nullptr, x1b);
    // 5. h = gelu(x1 @ W1 + bff1), 256^2 tile -> grid 16x16 = 1 block/CU
    gemm_gelu<<<dim3(FF/256, BT/256), 512, 0, stream>>>(x1b, W1t, bff1, hb, BT, FF, EMB);
    // 6+7. ff = h @ W2 split-K=2 (NT=32 at BK=64), then final LN.
    P4 fp; fp.p[0] = mp0; fp.p[1] = mp1; fp.p[2] = nullptr; fp.p[3] = nullptr;
    gemm_splitk<<<dim3(EMB/128, BT/128, 2), 256, 0, stream>>>(hb, W2t, fp, BT, EMB, FF, FF/2);
    ln_kernel<2, 1><<<dim3(BT), 256, 0, stream>>>(x1b, fp, bff2, g2, b2, out, nullptr);
}